// Round 2
// baseline (3758.855 us; speedup 1.0000x reference)
//
#include <hip/hip_runtime.h>
#include <hip/hip_bf16.h>
#include <math.h>

// ---------------- model constants ----------------
// B=8, C=64, T=4096; patch (2,16) stride (2,16) -> (E=64, G0=32, G1=256)
// tokens: (8, 256, 2048); DIN=4096, DS=16, DTR=128, DC=4; dirs=2 (fwd/rev)

// ---------------- patchify + pos embed ----------------
__global__ __launch_bounds__(256) void patchify_k(
    const float* __restrict__ x, const int* __restrict__ mask,
    const float* __restrict__ pw, const float* __restrict__ pb,
    const float* __restrict__ pos, float* __restrict__ h)
{
  int g1 = blockIdx.x;   // 0..255
  int b  = blockIdx.y;   // 0..7
  int tid = threadIdx.x;
  __shared__ float sX[64 * 17];
  __shared__ float sW[2048];
  for (int i = tid; i < 64 * 16; i += 256) {
    int r = i >> 4, c = i & 15;
    int gi = (b * 64 + r) * 4096 + g1 * 16 + c;
    float v = mask[gi] ? 0.f : x[gi];
    sX[r * 17 + c] = v;
  }
  for (int i = tid; i < 2048; i += 256) sW[i] = pw[i];
  __syncthreads();
  for (int m = tid; m < 2048; m += 256) {
    int e = m >> 5, g0 = m & 31;
    float acc = pb[e];
    const float* w = &sW[e * 32];
#pragma unroll
    for (int kh = 0; kh < 2; ++kh)
#pragma unroll
      for (int kw = 0; kw < 16; ++kw)
        acc += sX[(2 * g0 + kh) * 17 + kw] * w[kh * 16 + kw];
    h[((long)b * 256 + g1) * 2048 + m] = acc + pos[g1 * 2048 + m];
  }
}

// ---------------- generic fp32 GEMM: C[m,n] = sum_k A[m,k]*B[n,k] ----------------
// grid.z = dir. A optionally row-flipped within each 256-row batch (dir==1).
// EPI: 0 = none, 1 = softplus(v + bias[n])
template <int BM, int BN, int BK, int TM, int TN, int EPI>
__global__ __launch_bounds__(256) void gemm_nt(
    const float* __restrict__ A0, long aStride,
    const float* __restrict__ B0, long bStride,
    float* __restrict__ C0, long cStride,
    const float* __restrict__ bias0, int biasStride,
    int N, int K, int lda, int flipDir1)
{
  constexpr int TCOLS = BN / TN;
  constexpr int TROWS = BM / TM;
  static_assert(TCOLS * TROWS == 256, "thread mapping");
  constexpr int K4 = BK / 4;

  int dir = blockIdx.z;
  const float* A = A0 + (long)dir * aStride;
  const float* Bw = B0 + (long)dir * bStride;
  float* C = C0 + (long)dir * cStride;
  const float* bias = bias0 ? (bias0 + (long)dir * biasStride) : nullptr;
  int flip = flipDir1 && (dir == 1);

  __shared__ float As[BK][BM + 4];
  __shared__ float Bs[BK][BN + 4];

  int tid = threadIdx.x;
  int tc = tid % TCOLS, tr = tid / TCOLS;
  int bm = blockIdx.y * BM, bn = blockIdx.x * BN;

  float acc[TM][TN];
#pragma unroll
  for (int i = 0; i < TM; ++i)
#pragma unroll
    for (int j = 0; j < TN; ++j) acc[i][j] = 0.f;

  for (int k0 = 0; k0 < K; k0 += BK) {
    for (int i4 = tid; i4 < BM * K4; i4 += 256) {
      int row = i4 / K4, kk = (i4 % K4) * 4;
      int ar = bm + row;
      int arow = flip ? ((ar & ~255) | (255 - (ar & 255))) : ar;
      const float4 v = *reinterpret_cast<const float4*>(&A[(long)arow * lda + k0 + kk]);
      As[kk + 0][row] = v.x; As[kk + 1][row] = v.y;
      As[kk + 2][row] = v.z; As[kk + 3][row] = v.w;
    }
    for (int i4 = tid; i4 < BN * K4; i4 += 256) {
      int row = i4 / K4, kk = (i4 % K4) * 4;
      const float4 v = *reinterpret_cast<const float4*>(&Bw[(long)(bn + row) * K + k0 + kk]);
      Bs[kk + 0][row] = v.x; Bs[kk + 1][row] = v.y;
      Bs[kk + 2][row] = v.z; Bs[kk + 3][row] = v.w;
    }
    __syncthreads();
#pragma unroll
    for (int k = 0; k < BK; ++k) {
      float a[TM], bf[TN];
#pragma unroll
      for (int i = 0; i < TM; ++i) a[i] = As[k][tr * TM + i];
#pragma unroll
      for (int j = 0; j < TN; ++j) bf[j] = Bs[k][tc * TN + j];
#pragma unroll
      for (int i = 0; i < TM; ++i)
#pragma unroll
        for (int j = 0; j < TN; ++j) acc[i][j] += a[i] * bf[j];
    }
    __syncthreads();
  }

#pragma unroll
  for (int i = 0; i < TM; ++i) {
    long r = bm + tr * TM + i;
#pragma unroll
    for (int j = 0; j < TN; ++j) {
      int n = bn + tc * TN + j;
      float v = acc[i][j];
      if (EPI == 1) {
        v += bias[n];
        v = (v > 20.f) ? v : log1pf(expf(v));
      }
      C[r * N + n] = v;
    }
  }
}

// ---------------- depthwise causal conv1d (DC=4) + bias + silu ----------------
__global__ __launch_bounds__(256) void conv1d_silu_k(
    const float* __restrict__ xz, const float* __restrict__ cw,
    const float* __restrict__ cb, float* __restrict__ u)
{
  long idx = (long)blockIdx.x * 256 + threadIdx.x;  // [0, 2*8*256*1024)
  int d4 = (int)(idx & 1023);
  int l  = (int)((idx >> 10) & 255);
  int b  = (int)((idx >> 18) & 7);
  int dir = (int)(idx >> 21);
  int d = d4 * 4;
  const float4* wv = reinterpret_cast<const float4*>(cw + ((long)dir * 4096 + d) * 4);
  float4 w0 = wv[0], w1 = wv[1], w2 = wv[2], w3 = wv[3];
  const float* cbp = cb + dir * 4096 + d;
  float a0 = cbp[0], a1 = cbp[1], a2 = cbp[2], a3 = cbp[3];
  long rowstride = 8192;
  long base = (((long)dir * 8 + b) * 256) * 8192 + d;
#pragma unroll
  for (int k = 0; k < 4; ++k) {
    int lk = l - 3 + k;
    if (lk < 0) continue;
    float4 xv = *reinterpret_cast<const float4*>(xz + base + (long)lk * rowstride);
    a0 += xv.x * ((const float*)&w0)[k];
    a1 += xv.y * ((const float*)&w1)[k];
    a2 += xv.z * ((const float*)&w2)[k];
    a3 += xv.w * ((const float*)&w3)[k];
  }
  float4 r;
  r.x = a0 / (1.f + expf(-a0));
  r.y = a1 / (1.f + expf(-a1));
  r.z = a2 / (1.f + expf(-a2));
  r.w = a3 / (1.f + expf(-a3));
  *reinterpret_cast<float4*>(u + (((long)dir * 8 + b) * 256 + l) * 4096 + d) = r;
}

// ---------------- selective scan (L=256 steps), fused gating; y overwrites dt ----------------
__global__ __launch_bounds__(256) void scan_k(
    const float* __restrict__ dtbuf, const float* __restrict__ ubuf,
    const float* __restrict__ xz, const float* __restrict__ xdbl,
    const float* __restrict__ A_log, const float* __restrict__ Dpv,
    float* __restrict__ ybuf)
{
  int blk = blockIdx.x;          // 2*8*16 = 256 blocks
  int chunk = blk & 15, b = (blk >> 4) & 7, dir = blk >> 7;
  int d = chunk * 256 + threadIdx.x;
  float A[16], st[16];
#pragma unroll
  for (int s = 0; s < 16; ++s) {
    A[s] = -expf(A_log[((long)dir * 4096 + d) * 16 + s]);
    st[s] = 0.f;
  }
  float Dpd = Dpv[dir * 4096 + d];
  __shared__ float sBC[2][32];
  long r160 = (((long)dir * 8 + b) * 256) * 160;
  long r4096 = (((long)dir * 8 + b) * 256) * 4096;
  long r8192 = (((long)dir * 8 + b) * 256) * 8192;
  for (int l = 0; l < 256; ++l) {
    if (threadIdx.x < 32) sBC[l & 1][threadIdx.x] = xdbl[r160 + (long)l * 160 + 128 + threadIdx.x];
    __syncthreads();
    const float* BC = sBC[l & 1];
    float dtv = dtbuf[r4096 + (long)l * 4096 + d];
    float uv  = ubuf [r4096 + (long)l * 4096 + d];
    float zv  = xz   [r8192 + (long)l * 8192 + 4096 + d];
    float du = dtv * uv;
    float y = 0.f;
#pragma unroll
    for (int s = 0; s < 16; ++s) {
      st[s] = st[s] * expf(dtv * A[s]) + du * BC[s];
      y += st[s] * BC[16 + s];
    }
    float sig = 1.f / (1.f + expf(-zv));
    y = (y + uv * Dpd) * (zv * sig);
    ybuf[r4096 + (long)l * 4096 + d] = y;
  }
}

// ---------------- residual add (fwd + flipped rev) + LayerNorm ----------------
__global__ __launch_bounds__(256) void add_ln_k(
    const float* __restrict__ h, const float* __restrict__ o0,
    const float* __restrict__ o1, const float* __restrict__ g,
    const float* __restrict__ bta, float* __restrict__ h2)
{
  int row = blockIdx.x;  // b*256 + l
  int b = row >> 8, l = row & 255;
  long base = (long)row * 2048;
  long base1 = ((long)b * 256 + (255 - l)) * 2048;
  int t8 = threadIdx.x * 8;
  float v[8];
  float4 x0 = *(const float4*)(h + base + t8);
  float4 x1 = *(const float4*)(h + base + t8 + 4);
  float4 a0 = *(const float4*)(o0 + base + t8);
  float4 a1 = *(const float4*)(o0 + base + t8 + 4);
  float4 c0 = *(const float4*)(o1 + base1 + t8);
  float4 c1 = *(const float4*)(o1 + base1 + t8 + 4);
  v[0] = x0.x + a0.x + c0.x; v[1] = x0.y + a0.y + c0.y;
  v[2] = x0.z + a0.z + c0.z; v[3] = x0.w + a0.w + c0.w;
  v[4] = x1.x + a1.x + c1.x; v[5] = x1.y + a1.y + c1.y;
  v[6] = x1.z + a1.z + c1.z; v[7] = x1.w + a1.w + c1.w;
  float s = 0.f, ss = 0.f;
#pragma unroll
  for (int j = 0; j < 8; ++j) { s += v[j]; ss += v[j] * v[j]; }
#pragma unroll
  for (int off = 32; off >= 1; off >>= 1) {
    s += __shfl_xor(s, off, 64);
    ss += __shfl_xor(ss, off, 64);
  }
  __shared__ float red[8];
  int wid = threadIdx.x >> 6, lane = threadIdx.x & 63;
  if (lane == 0) { red[wid] = s; red[wid + 4] = ss; }
  __syncthreads();
  if (threadIdx.x == 0) {
    float S = red[0] + red[1] + red[2] + red[3];
    float SS = red[4] + red[5] + red[6] + red[7];
    red[0] = S; red[4] = SS;
  }
  __syncthreads();
  float mean = red[0] * (1.f / 2048.f);
  float var = red[4] * (1.f / 2048.f) - mean * mean;
  float inv = rsqrtf(var + 1e-5f);
  float o[8];
#pragma unroll
  for (int j = 0; j < 8; ++j)
    o[j] = (v[j] - mean) * inv * g[t8 + j] + bta[t8 + j];
  *(float4*)(h2 + base + t8) = make_float4(o[0], o[1], o[2], o[3]);
  *(float4*)(h2 + base + t8 + 4) = make_float4(o[4], o[5], o[6], o[7]);
}

// ---------------- 31x31 "same" conv on (256 x 2048) per batch ----------------
__global__ __launch_bounds__(256) void dec_conv31_k(
    const float* __restrict__ h2, const float* __restrict__ kw,
    float* __restrict__ dc)
{
  __shared__ float sIn[38 * 288];   // 43.8 KB
  int b = blockIdx.z;
  int l0 = blockIdx.y * 8;
  int m0 = blockIdx.x * 256;
  int tid = threadIdx.x;
  const float* src = h2 + (long)b * 256 * 2048;
  for (int i = tid; i < 38 * 288; i += 256) {
    int r = i / 288, c = i % 288;
    int gl = l0 + r - 15, gm = m0 + c - 15;
    float v = 0.f;
    if (c < 286 && gl >= 0 && gl < 256 && gm >= 0 && gm < 2048)
      v = src[(long)gl * 2048 + gm];
    sIn[i] = v;
  }
  __syncthreads();
  int ty = tid >> 5, tx = tid & 31;
  float acc[8];
#pragma unroll
  for (int c2 = 0; c2 < 8; ++c2) acc[c2] = 0.f;
  for (int ki = 0; ki < 31; ++ki) {
    const float* rowp = &sIn[(ty + ki) * 288 + tx * 8];
    float w[40];
#pragma unroll
    for (int q = 0; q < 10; ++q) {
      float4 t = *(const float4*)(rowp + q * 4);
      w[q * 4] = t.x; w[q * 4 + 1] = t.y; w[q * 4 + 2] = t.z; w[q * 4 + 3] = t.w;
    }
#pragma unroll
    for (int kj = 0; kj < 31; ++kj) {
      float kv = kw[ki * 31 + kj];
#pragma unroll
      for (int c2 = 0; c2 < 8; ++c2)
        acc[c2] += w[kj + c2] * kv;
    }
  }
  long obase = ((long)b * 256 + l0 + ty) * 2048 + m0 + tx * 8;
  *(float4*)(dc + obase) = make_float4(acc[0], acc[1], acc[2], acc[3]);
  *(float4*)(dc + obase + 4) = make_float4(acc[4], acc[5], acc[6], acc[7]);
}

// ---------------- fused transposed conv (stride 2x16) ----------------
// rec[b,oh,ow] = sum_e dc[b, ow>>4, e*32 + (oh>>1)] * W[e,0,oh&1,ow&15] + cb
__global__ __launch_bounds__(256) void convT_k(
    const float* __restrict__ dc, const float* __restrict__ w,
    const float* __restrict__ wb, float* __restrict__ out)
{
  int j = blockIdx.x;   // ow >> 4
  int b = blockIdx.y;
  __shared__ float sD[2048];
  __shared__ float sW[2048];
  int tid = threadIdx.x;
  const float* drow = dc + ((long)b * 256 + j) * 2048;
  for (int i = tid; i < 2048; i += 256) { sD[i] = drow[i]; sW[i] = w[i]; }
  __syncthreads();
  float cb = wb[0];
  int owlo = tid & 15, ohbase = tid >> 4;  // ohbase 0..15
#pragma unroll
  for (int q = 0; q < 4; ++q) {
    int oh = ohbase + q * 16;
    int i = oh >> 1, a = oh & 1;
    float acc = cb;
#pragma unroll 8
    for (int e = 0; e < 64; ++e)
      acc += sD[e * 32 + i] * sW[e * 32 + a * 16 + owlo];
    out[((long)b * 64 + oh) * 4096 + j * 16 + owlo] = acc;
  }
}

// ---------------- launcher ----------------
extern "C" void kernel_launch(void* const* d_in, const int* in_sizes, int n_in,
                              void* d_out, int out_size, void* d_ws, size_t ws_size,
                              hipStream_t stream)
{
  const float* x      = (const float*)d_in[0];
  const int*   mask   = (const int*)d_in[1];     // boolean -> int32 per harness
  const float* proj_w = (const float*)d_in[2];
  const float* proj_b = (const float*)d_in[3];
  const float* pos    = (const float*)d_in[4];
  const float* Wip    = (const float*)d_in[5];   // (1,2,8192,2048)
  const float* convw  = (const float*)d_in[6];   // (1,2,4096,4)
  const float* convb  = (const float*)d_in[7];   // (1,2,4096)
  const float* Wx     = (const float*)d_in[8];   // (1,2,160,4096)
  const float* Wdt    = (const float*)d_in[9];   // (1,2,4096,128)
  const float* bdt    = (const float*)d_in[10];  // (1,2,4096)
  const float* Alog   = (const float*)d_in[11];  // (1,2,4096,16)
  const float* Dpv    = (const float*)d_in[12];  // (1,2,4096)
  const float* Wout   = (const float*)d_in[13];  // (1,2,2048,4096)
  const float* lng    = (const float*)d_in[14];
  const float* lnb    = (const float*)d_in[15];
  const float* dkw    = (const float*)d_in[16];  // (1,1,31,31)
  const float* ctw    = (const float*)d_in[17];  // (64,1,2,16)
  const float* ctb    = (const float*)d_in[18];  // (1,)
  float* out = (float*)d_out;

  // workspace layout (floats); ob aliases xz (dead after scan),
  // dc aliases u (dead after scan)
  float* ws   = (float*)d_ws;
  float* xz   = ws;                    // 2*8*256*8192 = 33554432
  float* u    = xz + 33554432;         // 2*8*256*4096 = 16777216
  float* xdbl = u + 16777216;          // 2*8*256*160  = 655360
  float* dt   = xdbl + 655360;         // 16777216 (reused as y)
  float* h    = dt + 16777216;         // 4194304
  float* h2   = h + 4194304;           // 4194304
  float* ob   = xz;                    // alias: 2*2048*2048 = 8388608
  float* dc   = u;                     // alias: 8*256*2048  = 4194304

  // 1) patchify + pos embed -> h (8,256,2048)
  patchify_k<<<dim3(256, 8), 256, 0, stream>>>(x, mask, proj_w, proj_b, pos, h);

  // 2) in_proj: xz[dir] = (dir? flip(h):h) @ Win[dir]^T   (2048 x 8192, K=2048)
  gemm_nt<128, 128, 16, 8, 8, 0><<<dim3(64, 16, 2), 256, 0, stream>>>(
      h, 0L, Wip, (long)8192 * 2048, xz, (long)2048 * 8192, nullptr, 0,
      8192, 2048, 2048, 1);

  // 3) depthwise conv1d + silu -> u
  conv1d_silu_k<<<16384, 256, 0, stream>>>(xz, convw, convb, u);

  // 4) x_dbl = u @ Wx^T   (2048 x 160, K=4096)
  gemm_nt<64, 32, 16, 4, 2, 0><<<dim3(5, 32, 2), 256, 0, stream>>>(
      u, (long)2048 * 4096, Wx, (long)160 * 4096, xdbl, (long)2048 * 160,
      nullptr, 0, 160, 4096, 4096, 0);

  // 5) dt = softplus(x_dbl[:, :128] @ Wdt^T + bdt)   (2048 x 4096, K=128)
  gemm_nt<128, 128, 16, 8, 8, 1><<<dim3(32, 16, 2), 256, 0, stream>>>(
      xdbl, (long)2048 * 160, Wdt, (long)4096 * 128, dt, (long)2048 * 4096,
      bdt, 4096, 4096, 128, 160, 0);

  // 6) selective scan + gating -> y (in place over dt)
  scan_k<<<256, 256, 0, stream>>>(dt, u, xz, xdbl, Alog, Dpv, dt);

  // 7) out = y @ Wout^T   (2048 x 2048, K=4096)  [ob aliases xz: xz dead now]
  gemm_nt<128, 128, 16, 8, 8, 0><<<dim3(16, 16, 2), 256, 0, stream>>>(
      dt, (long)2048 * 4096, Wout, (long)2048 * 4096, ob, (long)2048 * 2048,
      nullptr, 0, 2048, 4096, 4096, 0);

  // 8) h2 = LN(h + o_fwd + flip(o_rev))
  add_ln_k<<<2048, 256, 0, stream>>>(h, ob, ob + (long)2048 * 2048, lng, lnb, h2);

  // 9) 31x31 same conv -> dc  [dc aliases u: u dead now]
  dec_conv31_k<<<dim3(8, 32, 8), 256, 0, stream>>>(h2, dkw, dc);

  // 10) fused transposed conv -> rec (first half of output)
  convT_k<<<dim3(256, 8), 256, 0, stream>>>(dc, ctw, ctb, out);

  // 11) second output: x passthrough
  hipMemcpyAsync(out + 2097152, x, (size_t)2097152 * 4,
                 hipMemcpyDeviceToDevice, stream);
}

// Round 3
// 1029.057 us; speedup vs baseline: 3.6527x; 3.6527x over previous
//
#include <hip/hip_runtime.h>
#include <hip/hip_bf16.h>
#include <math.h>

typedef unsigned short u16;
typedef __attribute__((ext_vector_type(8))) short bf16x8;
typedef __attribute__((ext_vector_type(4))) float f32x4;

__device__ __forceinline__ float b2f(u16 v) {
  unsigned u = ((unsigned)v) << 16;
  return __builtin_bit_cast(float, u);
}
__device__ __forceinline__ u16 f2b(float f) {
  unsigned u = __builtin_bit_cast(unsigned, f);
  unsigned r = u + 0x7fffu + ((u >> 16) & 1u);
  return (u16)(r >> 16);
}
__device__ __forceinline__ void gload_lds16(const u16* g, u16* l) {
  __builtin_amdgcn_global_load_lds(
      (const __attribute__((address_space(1))) void*)g,
      (__attribute__((address_space(3))) void*)l, 16, 0, 0);
}

// ---------------- fp32 -> bf16 convert ----------------
__global__ __launch_bounds__(256) void cvt_bf16_k(const float* __restrict__ s,
                                                  u16* __restrict__ d, int n4) {
  int i = blockIdx.x * 256 + threadIdx.x;
  if (i < n4) {
    float4 v = ((const float4*)s)[i];
    ushort4 o;
    o.x = f2b(v.x); o.y = f2b(v.y); o.z = f2b(v.z); o.w = f2b(v.w);
    ((ushort4*)d)[i] = o;
  }
}

// ---------------- patchify + pos embed -> h fp32 + h_bf ----------------
__global__ __launch_bounds__(256) void patchify_k(
    const float* __restrict__ x, const int* __restrict__ mask,
    const float* __restrict__ pw, const float* __restrict__ pb,
    const float* __restrict__ pos, float* __restrict__ h, u16* __restrict__ hb)
{
  int g1 = blockIdx.x, b = blockIdx.y, tid = threadIdx.x;
  __shared__ float sX[64 * 17];
  __shared__ float sW[2048];
  for (int i = tid; i < 64 * 16; i += 256) {
    int r = i >> 4, c = i & 15;
    int gi = (b * 64 + r) * 4096 + g1 * 16 + c;
    sX[r * 17 + c] = mask[gi] ? 0.f : x[gi];
  }
  for (int i = tid; i < 2048; i += 256) sW[i] = pw[i];
  __syncthreads();
  for (int m = tid; m < 2048; m += 256) {
    int e = m >> 5, g0 = m & 31;
    float acc = pb[e];
    const float* w = &sW[e * 32];
#pragma unroll
    for (int kh = 0; kh < 2; ++kh)
#pragma unroll
      for (int kw = 0; kw < 16; ++kw)
        acc += sX[(2 * g0 + kh) * 17 + kw] * w[kh * 16 + kw];
    float v = acc + pos[g1 * 2048 + m];
    long o = ((long)b * 256 + g1) * 2048 + m;
    h[o] = v;
    hb[o] = f2b(v);
  }
}

// ---------------- bf16 MFMA GEMM: C[m,n] = sum_k A[m,k]*B[n,k] ----------------
// 128x128 tile, BK=32, 4 waves (2x2 of 64x64), 16x16x32 MFMA, dbuf LDS via
// global_load_lds(16B). grid.z = dir. flip: reverse rows within 256-row batch.
template <int EPI, int F32OUT, int BFOUT>
__global__ __launch_bounds__(256) void mfma_gemm_k(
    const u16* __restrict__ A0, long aStride,
    const u16* __restrict__ B0, long bStride,
    float* __restrict__ C0, long cStride,
    u16* __restrict__ Cb0, long cbStride,
    const float* __restrict__ bias0, int biasStride,
    int N, int K, int lda, int flipDir1)
{
  __shared__ __align__(16) u16 As[2][4096];
  __shared__ __align__(16) u16 Bs[2][4096];
  const int dir = blockIdx.z;
  const u16* A = A0 + (long)dir * aStride;
  const u16* B = B0 + (long)dir * bStride;
  float* C = F32OUT ? (C0 + (long)dir * cStride) : nullptr;
  u16* Cb = BFOUT ? (Cb0 + (long)dir * cbStride) : nullptr;
  const float* bias = (EPI == 1) ? (bias0 + (long)dir * biasStride) : nullptr;
  const int flip = flipDir1 && (dir == 1);

  const int tid = threadIdx.x;
  const int wave = tid >> 6, lane = tid & 63;
  const int wr = wave >> 1, wc = wave & 1;
  const int bm = blockIdx.y * 128, bn = blockIdx.x * 128;
  const int lr = lane & 15, lq = lane >> 4;

  f32x4 acc[4][4];
#pragma unroll
  for (int i = 0; i < 4; ++i)
#pragma unroll
    for (int j = 0; j < 4; ++j) acc[i][j] = (f32x4){0.f, 0.f, 0.f, 0.f};

  const int nk = K >> 5;

  auto stage = [&](int buf, int k0) {
#pragma unroll
    for (int iss = 0; iss < 2; ++iss) {
      int ob = wave * 2048 + iss * 1024 + lane * 16;  // byte offset in tile
      int row = ob >> 6, kb = (ob >> 4) & 3;
      int rg = bm + row;
      rg = flip ? ((rg & ~255) | (255 - (rg & 255))) : rg;
      gload_lds16(A + (long)rg * lda + k0 + kb * 8,
                  &As[buf][wave * 1024 + iss * 512]);
      int rb = bn + row; rb = (rb < N) ? rb : (N - 1);
      gload_lds16(B + (long)rb * K + k0 + kb * 8,
                  &Bs[buf][wave * 1024 + iss * 512]);
    }
  };

  stage(0, 0);
  for (int kt = 0; kt < nk; ++kt) {
    __syncthreads();
    if (kt + 1 < nk) stage((kt + 1) & 1, (kt + 1) << 5);
    const int buf = kt & 1;
    bf16x8 av[4], bv[4];
#pragma unroll
    for (int i = 0; i < 4; ++i)
      av[i] = *(const bf16x8*)&As[buf][(wr * 64 + i * 16 + lr) * 32 + lq * 8];
#pragma unroll
    for (int j = 0; j < 4; ++j)
      bv[j] = *(const bf16x8*)&Bs[buf][(wc * 64 + j * 16 + lr) * 32 + lq * 8];
#pragma unroll
    for (int i = 0; i < 4; ++i)
#pragma unroll
      for (int j = 0; j < 4; ++j)
        acc[i][j] = __builtin_amdgcn_mfma_f32_16x16x32_bf16(av[i], bv[j],
                                                            acc[i][j], 0, 0, 0);
  }

#pragma unroll
  for (int i = 0; i < 4; ++i) {
    int r0 = bm + wr * 64 + i * 16 + lq * 4;
#pragma unroll
    for (int j = 0; j < 4; ++j) {
      int col = bn + wc * 64 + j * 16 + lr;
      if (col < N) {
        f32x4 v = acc[i][j];
#pragma unroll
        for (int r = 0; r < 4; ++r) {
          float xv = v[r];
          if (EPI == 1) {
            xv += bias[col];
            xv = (xv > 20.f) ? xv : log1pf(expf(xv));
          }
          if (F32OUT) C[(long)(r0 + r) * N + col] = xv;
          if (BFOUT) Cb[(long)(r0 + r) * N + col] = f2b(xv);
        }
      }
    }
  }
}

// ---------------- depthwise causal conv1d (DC=4) + bias + silu (bf16 io) -----
__global__ __launch_bounds__(256) void conv1d_silu_k(
    const u16* __restrict__ xz, const float* __restrict__ cw,
    const float* __restrict__ cb, u16* __restrict__ u)
{
  long idx = (long)blockIdx.x * 256 + threadIdx.x;
  int d4 = (int)(idx & 1023);
  int l  = (int)((idx >> 10) & 255);
  int b  = (int)((idx >> 18) & 7);
  int dir = (int)(idx >> 21);
  int d = d4 * 4;
  const float4* wv = reinterpret_cast<const float4*>(cw + ((long)dir * 4096 + d) * 4);
  float4 w0 = wv[0], w1 = wv[1], w2 = wv[2], w3 = wv[3];
  const float* cbp = cb + dir * 4096 + d;
  float a0 = cbp[0], a1 = cbp[1], a2 = cbp[2], a3 = cbp[3];
  long base = (((long)dir * 8 + b) * 256) * 8192 + d;
#pragma unroll
  for (int k = 0; k < 4; ++k) {
    int lk = l - 3 + k;
    if (lk < 0) continue;
    ushort4 xv = *reinterpret_cast<const ushort4*>(xz + base + (long)lk * 8192);
    a0 += b2f(xv.x) * ((const float*)&w0)[k];
    a1 += b2f(xv.y) * ((const float*)&w1)[k];
    a2 += b2f(xv.z) * ((const float*)&w2)[k];
    a3 += b2f(xv.w) * ((const float*)&w3)[k];
  }
  ushort4 r;
  r.x = f2b(a0 / (1.f + __expf(-a0)));
  r.y = f2b(a1 / (1.f + __expf(-a1)));
  r.z = f2b(a2 / (1.f + __expf(-a2)));
  r.w = f2b(a3 / (1.f + __expf(-a3)));
  *reinterpret_cast<ushort4*>(u + (((long)dir * 8 + b) * 256 + l) * 4096 + d) = r;
}

// ---------------- selective scan (256 steps) + gating -> y_bf ----------------
__global__ __launch_bounds__(256) void scan_k(
    const float* __restrict__ dtbuf, const u16* __restrict__ ubuf,
    const u16* __restrict__ xzbf, const float* __restrict__ xdbl,
    const float* __restrict__ A_log, const float* __restrict__ Dpv,
    u16* __restrict__ ybuf)
{
  int blk = blockIdx.x;          // 2*8*16 = 256
  int chunk = blk & 15, b = (blk >> 4) & 7, dir = blk >> 7;
  int d = chunk * 256 + threadIdx.x;
  float A[16], st[16];
#pragma unroll
  for (int s = 0; s < 16; ++s) {
    A[s] = -__expf(A_log[((long)dir * 4096 + d) * 16 + s]);
    st[s] = 0.f;
  }
  float Dpd = Dpv[dir * 4096 + d];
  __shared__ float sBC[2][32];
  long r160  = (((long)dir * 8 + b) * 256) * 160;
  long r4096 = (((long)dir * 8 + b) * 256) * 4096;
  long r8192 = (((long)dir * 8 + b) * 256) * 8192;
  if (threadIdx.x < 32) sBC[0][threadIdx.x] = xdbl[r160 + 128 + threadIdx.x];
  float dtc = dtbuf[r4096 + d];
  float uc  = b2f(ubuf[r4096 + d]);
  float zc  = b2f(xzbf[r8192 + 4096 + d]);
  __syncthreads();
  for (int l = 0; l < 256; ++l) {
    float dtn = 0.f, un = 0.f, zn = 0.f;
    if (l < 255) {
      dtn = dtbuf[r4096 + (long)(l + 1) * 4096 + d];
      un  = b2f(ubuf[r4096 + (long)(l + 1) * 4096 + d]);
      zn  = b2f(xzbf[r8192 + (long)(l + 1) * 8192 + 4096 + d]);
      if (threadIdx.x < 32)
        sBC[(l + 1) & 1][threadIdx.x] = xdbl[r160 + (long)(l + 1) * 160 + 128 + threadIdx.x];
    }
    const float* BC = sBC[l & 1];
    float du = dtc * uc;
    float y = 0.f;
#pragma unroll
    for (int s = 0; s < 16; ++s) {
      st[s] = st[s] * __expf(dtc * A[s]) + du * BC[s];
      y += st[s] * BC[16 + s];
    }
    float sig = 1.f / (1.f + __expf(-zc));
    y = (y + uc * Dpd) * (zc * sig);
    ybuf[r4096 + (long)l * 4096 + d] = f2b(y);
    dtc = dtn; uc = un; zc = zn;
    __syncthreads();
  }
}

// ---------------- residual add (fwd + flipped rev) + LayerNorm ----------------
__global__ __launch_bounds__(256) void add_ln_k(
    const float* __restrict__ h, const float* __restrict__ o0,
    const float* __restrict__ o1, const float* __restrict__ g,
    const float* __restrict__ bta, float* __restrict__ h2)
{
  int row = blockIdx.x;
  int b = row >> 8, l = row & 255;
  long base = (long)row * 2048;
  long base1 = ((long)b * 256 + (255 - l)) * 2048;
  int t8 = threadIdx.x * 8;
  float v[8];
  float4 x0 = *(const float4*)(h + base + t8);
  float4 x1 = *(const float4*)(h + base + t8 + 4);
  float4 a0 = *(const float4*)(o0 + base + t8);
  float4 a1 = *(const float4*)(o0 + base + t8 + 4);
  float4 c0 = *(const float4*)(o1 + base1 + t8);
  float4 c1 = *(const float4*)(o1 + base1 + t8 + 4);
  v[0] = x0.x + a0.x + c0.x; v[1] = x0.y + a0.y + c0.y;
  v[2] = x0.z + a0.z + c0.z; v[3] = x0.w + a0.w + c0.w;
  v[4] = x1.x + a1.x + c1.x; v[5] = x1.y + a1.y + c1.y;
  v[6] = x1.z + a1.z + c1.z; v[7] = x1.w + a1.w + c1.w;
  float s = 0.f, ss = 0.f;
#pragma unroll
  for (int j = 0; j < 8; ++j) { s += v[j]; ss += v[j] * v[j]; }
#pragma unroll
  for (int off = 32; off >= 1; off >>= 1) {
    s += __shfl_xor(s, off, 64);
    ss += __shfl_xor(ss, off, 64);
  }
  __shared__ float red[8];
  int wid = threadIdx.x >> 6, lane = threadIdx.x & 63;
  if (lane == 0) { red[wid] = s; red[wid + 4] = ss; }
  __syncthreads();
  if (threadIdx.x == 0) {
    red[0] = red[0] + red[1] + red[2] + red[3];
    red[4] = red[4] + red[5] + red[6] + red[7];
  }
  __syncthreads();
  float mean = red[0] * (1.f / 2048.f);
  float var = red[4] * (1.f / 2048.f) - mean * mean;
  float inv = rsqrtf(var + 1e-5f);
  float o[8];
#pragma unroll
  for (int j = 0; j < 8; ++j)
    o[j] = (v[j] - mean) * inv * g[t8 + j] + bta[t8 + j];
  *(float4*)(h2 + base + t8) = make_float4(o[0], o[1], o[2], o[3]);
  *(float4*)(h2 + base + t8 + 4) = make_float4(o[4], o[5], o[6], o[7]);
}

// ---------------- 31x31 "same" conv on (256 x 2048) per batch ----------------
__global__ __launch_bounds__(256) void dec_conv31_k(
    const float* __restrict__ h2, const float* __restrict__ kw,
    float* __restrict__ dc)
{
  __shared__ float sIn[38 * 288];
  int b = blockIdx.z;
  int l0 = blockIdx.y * 8;
  int m0 = blockIdx.x * 256;
  int tid = threadIdx.x;
  const float* src = h2 + (long)b * 256 * 2048;
  for (int i = tid; i < 38 * 288; i += 256) {
    int r = i / 288, c = i % 288;
    int gl = l0 + r - 15, gm = m0 + c - 15;
    float v = 0.f;
    if (c < 286 && gl >= 0 && gl < 256 && gm >= 0 && gm < 2048)
      v = src[(long)gl * 2048 + gm];
    sIn[i] = v;
  }
  __syncthreads();
  int ty = tid >> 5, tx = tid & 31;
  float acc[8];
#pragma unroll
  for (int c2 = 0; c2 < 8; ++c2) acc[c2] = 0.f;
  for (int ki = 0; ki < 31; ++ki) {
    const float* rowp = &sIn[(ty + ki) * 288 + tx * 8];
    float w[40];
#pragma unroll
    for (int q = 0; q < 10; ++q) {
      float4 t = *(const float4*)(rowp + q * 4);
      w[q * 4] = t.x; w[q * 4 + 1] = t.y; w[q * 4 + 2] = t.z; w[q * 4 + 3] = t.w;
    }
#pragma unroll
    for (int kj = 0; kj < 31; ++kj) {
      float kv = kw[ki * 31 + kj];
#pragma unroll
      for (int c2 = 0; c2 < 8; ++c2)
        acc[c2] += w[kj + c2] * kv;
    }
  }
  long obase = ((long)b * 256 + l0 + ty) * 2048 + m0 + tx * 8;
  *(float4*)(dc + obase) = make_float4(acc[0], acc[1], acc[2], acc[3]);
  *(float4*)(dc + obase + 4) = make_float4(acc[4], acc[5], acc[6], acc[7]);
}

// ---------------- fused transposed conv (stride 2x16) ----------------
__global__ __launch_bounds__(256) void convT_k(
    const float* __restrict__ dc, const float* __restrict__ w,
    const float* __restrict__ wb, float* __restrict__ out)
{
  int j = blockIdx.x, b = blockIdx.y;
  __shared__ float sD[2048];
  __shared__ float sW[2048];
  int tid = threadIdx.x;
  const float* drow = dc + ((long)b * 256 + j) * 2048;
  for (int i = tid; i < 2048; i += 256) { sD[i] = drow[i]; sW[i] = w[i]; }
  __syncthreads();
  float cb = wb[0];
  int owlo = tid & 15, ohbase = tid >> 4;
#pragma unroll
  for (int q = 0; q < 4; ++q) {
    int oh = ohbase + q * 16;
    int i = oh >> 1, a = oh & 1;
    float acc = cb;
#pragma unroll 8
    for (int e = 0; e < 64; ++e)
      acc += sD[e * 32 + i] * sW[e * 32 + a * 16 + owlo];
    out[((long)b * 64 + oh) * 4096 + j * 16 + owlo] = acc;
  }
}

// ---------------- launcher ----------------
extern "C" void kernel_launch(void* const* d_in, const int* in_sizes, int n_in,
                              void* d_out, int out_size, void* d_ws, size_t ws_size,
                              hipStream_t stream)
{
  const float* x      = (const float*)d_in[0];
  const int*   mask   = (const int*)d_in[1];
  const float* proj_w = (const float*)d_in[2];
  const float* proj_b = (const float*)d_in[3];
  const float* pos    = (const float*)d_in[4];
  const float* Wip    = (const float*)d_in[5];   // (1,2,8192,2048)
  const float* convw  = (const float*)d_in[6];
  const float* convb  = (const float*)d_in[7];
  const float* Wx     = (const float*)d_in[8];   // (1,2,160,4096)
  const float* Wdt    = (const float*)d_in[9];   // (1,2,4096,128)
  const float* bdt    = (const float*)d_in[10];
  const float* Alog   = (const float*)d_in[11];
  const float* Dpv    = (const float*)d_in[12];
  const float* Wout   = (const float*)d_in[13];  // (1,2,2048,4096)
  const float* lng    = (const float*)d_in[14];
  const float* lnb    = (const float*)d_in[15];
  const float* dkw    = (const float*)d_in[16];
  const float* ctw    = (const float*)d_in[17];
  const float* ctb    = (const float*)d_in[18];
  float* out = (float*)d_out;

  // workspace layout (bytes)
  char* p = (char*)d_ws;
  u16*   xz_bf   = (u16*)p;            // 33.5M u16 (67MB); later ob fp32 alias
  float* ob      = (float*)p;          //   8.4M f (33.5MB), written after scan
  p += 67108864;
  u16*   u_bf    = (u16*)p;            // 16.7M u16 (33.5MB); later dc alias
  float* dc      = (float*)p;          //   4.2M f (16.8MB), written after scan
  p += 33554432;
  float* dt      = (float*)p; p += 67108864;   // 16.7M f
  float* xdbl    = (float*)p; p += 2621440;    // 0.66M f
  u16*   xdbl_bf = (u16*)p;  p += 1310720;     // 0.66M u16
  float* h       = (float*)p; p += 16777216;   // 4.2M f
  u16*   h_bf    = (u16*)p;  p += 8388608;     // 4.2M u16
  float* h2      = (float*)p; p += 16777216;   // 4.2M f
  u16*   y_bf    = (u16*)p;  p += 33554432;    // 16.7M u16
  u16*   Wpool   = (u16*)p;  p += 67108864;    // 33.5M u16 (Wip_bf then Wout_bf)
  u16*   Wx_bf   = (u16*)p;  p += 2621440;     // 1.31M u16
  u16*   Wdt_bf  = (u16*)p;  p += 2097152;     // 1.05M u16

  // weight converts (Wip now; Wout later into same pool)
  cvt_bf16_k<<<32768, 256, 0, stream>>>(Wip, Wpool, 8388608);
  cvt_bf16_k<<<1280, 256, 0, stream>>>(Wx, Wx_bf, 327680);
  cvt_bf16_k<<<1024, 256, 0, stream>>>(Wdt, Wdt_bf, 262144);

  // 1) patchify + pos embed
  patchify_k<<<dim3(256, 8), 256, 0, stream>>>(x, mask, proj_w, proj_b, pos, h, h_bf);

  // 2) in_proj: xz_bf[dir] = (dir? flip(h):h) @ Wip[dir]^T  (2048x8192, K=2048)
  mfma_gemm_k<0, 0, 1><<<dim3(64, 16, 2), 256, 0, stream>>>(
      h_bf, 0L, Wpool, (long)8192 * 2048, nullptr, 0L, xz_bf, (long)2048 * 8192,
      nullptr, 0, 8192, 2048, 2048, 1);

  // 3) depthwise conv1d + silu -> u_bf
  conv1d_silu_k<<<16384, 256, 0, stream>>>(xz_bf, convw, convb, u_bf);

  // 4) x_dbl = u @ Wx^T  (2048x160, K=4096), fp32 + bf16 mirror
  mfma_gemm_k<0, 1, 1><<<dim3(2, 16, 2), 256, 0, stream>>>(
      u_bf, (long)2048 * 4096, Wx_bf, (long)160 * 4096, xdbl, (long)2048 * 160,
      xdbl_bf, (long)2048 * 160, nullptr, 0, 160, 4096, 4096, 0);

  // 5) dt = softplus(x_dbl[:, :128] @ Wdt^T + bdt)  (2048x4096, K=128)
  mfma_gemm_k<1, 1, 0><<<dim3(32, 16, 2), 256, 0, stream>>>(
      xdbl_bf, (long)2048 * 160, Wdt_bf, (long)4096 * 128, dt, (long)2048 * 4096,
      nullptr, 0L, bdt, 4096, 4096, 128, 160, 0);

  // 6) selective scan + gating -> y_bf
  scan_k<<<256, 256, 0, stream>>>(dt, u_bf, xz_bf, xdbl, Alog, Dpv, y_bf);

  // convert Wout into the (now dead) Wip pool
  cvt_bf16_k<<<16384, 256, 0, stream>>>(Wout, Wpool, 4194304);

  // 7) out = y @ Wout^T  (2048x2048, K=4096)  [ob aliases xz_bf region]
  mfma_gemm_k<0, 1, 0><<<dim3(16, 16, 2), 256, 0, stream>>>(
      y_bf, (long)2048 * 4096, Wpool, (long)2048 * 4096, ob, (long)2048 * 2048,
      nullptr, 0L, nullptr, 0, 2048, 4096, 4096, 0);

  // 8) h2 = LN(h + o_fwd + flip(o_rev))
  add_ln_k<<<2048, 256, 0, stream>>>(h, ob, ob + (long)2048 * 2048, lng, lnb, h2);

  // 9) 31x31 same conv -> dc  [aliases u_bf region, dead]
  dec_conv31_k<<<dim3(8, 32, 8), 256, 0, stream>>>(h2, dkw, dc);

  // 10) fused transposed conv -> rec
  convT_k<<<dim3(256, 8), 256, 0, stream>>>(dc, ctw, ctb, out);

  // 11) second output: x passthrough
  hipMemcpyAsync(out + 2097152, x, (size_t)2097152 * 4,
                 hipMemcpyDeviceToDevice, stream);
}

// Round 4
// 948.418 us; speedup vs baseline: 3.9633x; 1.0850x over previous
//
#include <hip/hip_runtime.h>
#include <hip/hip_bf16.h>
#include <math.h>

typedef unsigned short u16;
typedef __attribute__((ext_vector_type(8))) short bf16x8;
typedef __attribute__((ext_vector_type(4))) float f32x4;

__device__ __forceinline__ float b2f(u16 v) {
  unsigned u = ((unsigned)v) << 16;
  return __builtin_bit_cast(float, u);
}
__device__ __forceinline__ u16 f2b(float f) {
  unsigned u = __builtin_bit_cast(unsigned, f);
  unsigned r = u + 0x7fffu + ((u >> 16) & 1u);
  return (u16)(r >> 16);
}
__device__ __forceinline__ void gload_lds16(const u16* g, u16* l) {
  __builtin_amdgcn_global_load_lds(
      (const __attribute__((address_space(1))) void*)g,
      (__attribute__((address_space(3))) void*)l, 16, 0, 0);
}

// ---------------- fp32 -> bf16 convert ----------------
__global__ __launch_bounds__(256) void cvt_bf16_k(const float* __restrict__ s,
                                                  u16* __restrict__ d, int n4) {
  int i = blockIdx.x * 256 + threadIdx.x;
  if (i < n4) {
    float4 v = ((const float4*)s)[i];
    ushort4 o;
    o.x = f2b(v.x); o.y = f2b(v.y); o.z = f2b(v.z); o.w = f2b(v.w);
    ((ushort4*)d)[i] = o;
  }
}

// ---------------- patchify + pos embed -> h fp32 + h_bf ----------------
__global__ __launch_bounds__(256) void patchify_k(
    const float* __restrict__ x, const int* __restrict__ mask,
    const float* __restrict__ pw, const float* __restrict__ pb,
    const float* __restrict__ pos, float* __restrict__ h, u16* __restrict__ hb)
{
  int g1 = blockIdx.x, b = blockIdx.y, tid = threadIdx.x;
  __shared__ float sX[64 * 17];
  __shared__ float sW[2048];
  for (int i = tid; i < 64 * 16; i += 256) {
    int r = i >> 4, c = i & 15;
    int gi = (b * 64 + r) * 4096 + g1 * 16 + c;
    sX[r * 17 + c] = mask[gi] ? 0.f : x[gi];
  }
  for (int i = tid; i < 2048; i += 256) sW[i] = pw[i];
  __syncthreads();
  for (int m = tid; m < 2048; m += 256) {
    int e = m >> 5, g0 = m & 31;
    float acc = pb[e];
    const float* w = &sW[e * 32];
#pragma unroll
    for (int kh = 0; kh < 2; ++kh)
#pragma unroll
      for (int kw = 0; kw < 16; ++kw)
        acc += sX[(2 * g0 + kh) * 17 + kw] * w[kh * 16 + kw];
    float v = acc + pos[g1 * 2048 + m];
    long o = ((long)b * 256 + g1) * 2048 + m;
    h[o] = v;
    hb[o] = f2b(v);
  }
}

// ---------------- bf16 MFMA GEMM: C[m,n] = sum_k A[m,k]*B[n,k] ----------------
template <int EPI, int F32OUT, int BFOUT>
__global__ __launch_bounds__(256) void mfma_gemm_k(
    const u16* __restrict__ A0, long aStride,
    const u16* __restrict__ B0, long bStride,
    float* __restrict__ C0, long cStride,
    u16* __restrict__ Cb0, long cbStride,
    const float* __restrict__ bias0, int biasStride,
    int N, int K, int lda, int flipDir1)
{
  __shared__ __align__(16) u16 As[2][4096];
  __shared__ __align__(16) u16 Bs[2][4096];
  const int dir = blockIdx.z;
  const u16* A = A0 + (long)dir * aStride;
  const u16* B = B0 + (long)dir * bStride;
  float* C = F32OUT ? (C0 + (long)dir * cStride) : nullptr;
  u16* Cb = BFOUT ? (Cb0 + (long)dir * cbStride) : nullptr;
  const float* bias = (EPI == 1) ? (bias0 + (long)dir * biasStride) : nullptr;
  const int flip = flipDir1 && (dir == 1);

  const int tid = threadIdx.x;
  const int wave = tid >> 6, lane = tid & 63;
  const int wr = wave >> 1, wc = wave & 1;
  const int bm = blockIdx.y * 128, bn = blockIdx.x * 128;
  const int lr = lane & 15, lq = lane >> 4;

  f32x4 acc[4][4];
#pragma unroll
  for (int i = 0; i < 4; ++i)
#pragma unroll
    for (int j = 0; j < 4; ++j) acc[i][j] = (f32x4){0.f, 0.f, 0.f, 0.f};

  const int nk = K >> 5;

  auto stage = [&](int buf, int k0) {
#pragma unroll
    for (int iss = 0; iss < 2; ++iss) {
      int ob = wave * 2048 + iss * 1024 + lane * 16;  // byte offset in tile
      int row = ob >> 6, kb = (ob >> 4) & 3;
      int rg = bm + row;
      rg = flip ? ((rg & ~255) | (255 - (rg & 255))) : rg;
      gload_lds16(A + (long)rg * lda + k0 + kb * 8,
                  &As[buf][wave * 1024 + iss * 512]);
      int rb = bn + row; rb = (rb < N) ? rb : (N - 1);
      gload_lds16(B + (long)rb * K + k0 + kb * 8,
                  &Bs[buf][wave * 1024 + iss * 512]);
    }
  };

  stage(0, 0);
  for (int kt = 0; kt < nk; ++kt) {
    __syncthreads();
    if (kt + 1 < nk) stage((kt + 1) & 1, (kt + 1) << 5);
    const int buf = kt & 1;
    bf16x8 av[4], bv[4];
#pragma unroll
    for (int i = 0; i < 4; ++i)
      av[i] = *(const bf16x8*)&As[buf][(wr * 64 + i * 16 + lr) * 32 + lq * 8];
#pragma unroll
    for (int j = 0; j < 4; ++j)
      bv[j] = *(const bf16x8*)&Bs[buf][(wc * 64 + j * 16 + lr) * 32 + lq * 8];
#pragma unroll
    for (int i = 0; i < 4; ++i)
#pragma unroll
      for (int j = 0; j < 4; ++j)
        acc[i][j] = __builtin_amdgcn_mfma_f32_16x16x32_bf16(av[i], bv[j],
                                                            acc[i][j], 0, 0, 0);
  }

#pragma unroll
  for (int i = 0; i < 4; ++i) {
    int r0 = bm + wr * 64 + i * 16 + lq * 4;
#pragma unroll
    for (int j = 0; j < 4; ++j) {
      int col = bn + wc * 64 + j * 16 + lr;
      if (col < N) {
        f32x4 v = acc[i][j];
#pragma unroll
        for (int r = 0; r < 4; ++r) {
          float xv = v[r];
          if (EPI == 1) {
            xv += bias[col];
            xv = (xv > 20.f) ? xv : log1pf(expf(xv));
          }
          if (F32OUT) C[(long)(r0 + r) * N + col] = xv;
          if (BFOUT) Cb[(long)(r0 + r) * N + col] = f2b(xv);
        }
      }
    }
  }
}

// ---------------- depthwise causal conv1d (DC=4) + bias + silu (bf16 io) -----
__global__ __launch_bounds__(256) void conv1d_silu_k(
    const u16* __restrict__ xz, const float* __restrict__ cw,
    const float* __restrict__ cb, u16* __restrict__ u)
{
  long idx = (long)blockIdx.x * 256 + threadIdx.x;
  int d4 = (int)(idx & 1023);
  int l  = (int)((idx >> 10) & 255);
  int b  = (int)((idx >> 18) & 7);
  int dir = (int)(idx >> 21);
  int d = d4 * 4;
  const float4* wv = reinterpret_cast<const float4*>(cw + ((long)dir * 4096 + d) * 4);
  float4 w0 = wv[0], w1 = wv[1], w2 = wv[2], w3 = wv[3];
  const float* cbp = cb + dir * 4096 + d;
  float a0 = cbp[0], a1 = cbp[1], a2 = cbp[2], a3 = cbp[3];
  long base = (((long)dir * 8 + b) * 256) * 8192 + d;
#pragma unroll
  for (int k = 0; k < 4; ++k) {
    int lk = l - 3 + k;
    if (lk < 0) continue;
    ushort4 xv = *reinterpret_cast<const ushort4*>(xz + base + (long)lk * 8192);
    a0 += b2f(xv.x) * ((const float*)&w0)[k];
    a1 += b2f(xv.y) * ((const float*)&w1)[k];
    a2 += b2f(xv.z) * ((const float*)&w2)[k];
    a3 += b2f(xv.w) * ((const float*)&w3)[k];
  }
  ushort4 r;
  r.x = f2b(a0 / (1.f + __expf(-a0)));
  r.y = f2b(a1 / (1.f + __expf(-a1)));
  r.z = f2b(a2 / (1.f + __expf(-a2)));
  r.w = f2b(a3 / (1.f + __expf(-a3)));
  *reinterpret_cast<ushort4*>(u + (((long)dir * 8 + b) * 256 + l) * 4096 + d) = r;
}

// ---------------- selective scan (256 steps) + gating -> y_bf ----------------
__global__ __launch_bounds__(256) void scan_k(
    const float* __restrict__ dtbuf, const u16* __restrict__ ubuf,
    const u16* __restrict__ xzbf, const float* __restrict__ xdbl,
    const float* __restrict__ A_log, const float* __restrict__ Dpv,
    u16* __restrict__ ybuf)
{
  int blk = blockIdx.x;          // 2*8*16 = 256
  int chunk = blk & 15, b = (blk >> 4) & 7, dir = blk >> 7;
  int d = chunk * 256 + threadIdx.x;
  float A[16], st[16];
#pragma unroll
  for (int s = 0; s < 16; ++s) {
    A[s] = -__expf(A_log[((long)dir * 4096 + d) * 16 + s]);
    st[s] = 0.f;
  }
  float Dpd = Dpv[dir * 4096 + d];
  __shared__ float sBC[2][32];
  long r160  = (((long)dir * 8 + b) * 256) * 160;
  long r4096 = (((long)dir * 8 + b) * 256) * 4096;
  long r8192 = (((long)dir * 8 + b) * 256) * 8192;
  if (threadIdx.x < 32) sBC[0][threadIdx.x] = xdbl[r160 + 128 + threadIdx.x];
  float dtc = dtbuf[r4096 + d];
  float uc  = b2f(ubuf[r4096 + d]);
  float zc  = b2f(xzbf[r8192 + 4096 + d]);
  __syncthreads();
  for (int l = 0; l < 256; ++l) {
    float dtn = 0.f, un = 0.f, zn = 0.f;
    if (l < 255) {
      dtn = dtbuf[r4096 + (long)(l + 1) * 4096 + d];
      un  = b2f(ubuf[r4096 + (long)(l + 1) * 4096 + d]);
      zn  = b2f(xzbf[r8192 + (long)(l + 1) * 8192 + 4096 + d]);
      if (threadIdx.x < 32)
        sBC[(l + 1) & 1][threadIdx.x] = xdbl[r160 + (long)(l + 1) * 160 + 128 + threadIdx.x];
    }
    const float* BC = sBC[l & 1];
    float du = dtc * uc;
    float y = 0.f;
#pragma unroll
    for (int s = 0; s < 16; ++s) {
      st[s] = st[s] * __expf(dtc * A[s]) + du * BC[s];
      y += st[s] * BC[16 + s];
    }
    float sig = 1.f / (1.f + __expf(-zc));
    y = (y + uc * Dpd) * (zc * sig);
    ybuf[r4096 + (long)l * 4096 + d] = f2b(y);
    dtc = dtn; uc = un; zc = zn;
    __syncthreads();
  }
}

// ---------------- residual add (fwd + flipped rev) + LayerNorm ----------------
__global__ __launch_bounds__(256) void add_ln_k(
    const float* __restrict__ h, const float* __restrict__ o0,
    const float* __restrict__ o1, const float* __restrict__ g,
    const float* __restrict__ bta, float* __restrict__ h2)
{
  int row = blockIdx.x;
  int b = row >> 8, l = row & 255;
  long base = (long)row * 2048;
  long base1 = ((long)b * 256 + (255 - l)) * 2048;
  int t8 = threadIdx.x * 8;
  float v[8];
  float4 x0 = *(const float4*)(h + base + t8);
  float4 x1 = *(const float4*)(h + base + t8 + 4);
  float4 a0 = *(const float4*)(o0 + base + t8);
  float4 a1 = *(const float4*)(o0 + base + t8 + 4);
  float4 c0 = *(const float4*)(o1 + base1 + t8);
  float4 c1 = *(const float4*)(o1 + base1 + t8 + 4);
  v[0] = x0.x + a0.x + c0.x; v[1] = x0.y + a0.y + c0.y;
  v[2] = x0.z + a0.z + c0.z; v[3] = x0.w + a0.w + c0.w;
  v[4] = x1.x + a1.x + c1.x; v[5] = x1.y + a1.y + c1.y;
  v[6] = x1.z + a1.z + c1.z; v[7] = x1.w + a1.w + c1.w;
  float s = 0.f, ss = 0.f;
#pragma unroll
  for (int j = 0; j < 8; ++j) { s += v[j]; ss += v[j] * v[j]; }
#pragma unroll
  for (int off = 32; off >= 1; off >>= 1) {
    s += __shfl_xor(s, off, 64);
    ss += __shfl_xor(ss, off, 64);
  }
  __shared__ float red[8];
  int wid = threadIdx.x >> 6, lane = threadIdx.x & 63;
  if (lane == 0) { red[wid] = s; red[wid + 4] = ss; }
  __syncthreads();
  if (threadIdx.x == 0) {
    red[0] = red[0] + red[1] + red[2] + red[3];
    red[4] = red[4] + red[5] + red[6] + red[7];
  }
  __syncthreads();
  float mean = red[0] * (1.f / 2048.f);
  float var = red[4] * (1.f / 2048.f) - mean * mean;
  float inv = rsqrtf(var + 1e-5f);
  float o[8];
#pragma unroll
  for (int j = 0; j < 8; ++j)
    o[j] = (v[j] - mean) * inv * g[t8 + j] + bta[t8 + j];
  *(float4*)(h2 + base + t8) = make_float4(o[0], o[1], o[2], o[3]);
  *(float4*)(h2 + base + t8 + 4) = make_float4(o[4], o[5], o[6], o[7]);
}

// ---------------- 31x31 "same" conv, 64x128 tile, 4x8 per thread -------------
// LDS stride 162 (!%32) kills bank alignment; each input row in the thread's
// register window serves up to 4 output rows (ki offsets share loads).
__global__ __launch_bounds__(256) void dec_conv31_k(
    const float* __restrict__ h2, const float* __restrict__ kw,
    float* __restrict__ dc)
{
  __shared__ float sIn[94 * 162];   // 60912 B
  __shared__ float sKw[961];        //  3844 B
  int b = blockIdx.z;
  int l0 = blockIdx.y * 64;
  int m0 = blockIdx.x * 128;
  int tid = threadIdx.x;
  const float* src = h2 + (long)b * 256 * 2048;
  for (int i = tid; i < 961; i += 256) sKw[i] = kw[i];
  for (int i = tid; i < 94 * 162; i += 256) {
    int r = i / 162, c = i - r * 162;
    int gl = l0 + r - 15, gm = m0 + c - 15;
    float v = 0.f;
    if (c < 158 && gl >= 0 && gl < 256 && gm >= 0 && gm < 2048)
      v = src[(long)gl * 2048 + gm];
    sIn[i] = v;
  }
  __syncthreads();
  int tx = tid & 15, ty = tid >> 4;   // tx: col-octet 0..15, ty: row-quad 0..15
  float acc[4][8];
#pragma unroll
  for (int r = 0; r < 4; ++r)
#pragma unroll
    for (int c = 0; c < 8; ++c) acc[r][c] = 0.f;

#pragma unroll 1
  for (int k = 0; k < 34; ++k) {
    const float* rowp = &sIn[(ty * 4 + k) * 162 + tx * 8];
    float w[40];
#pragma unroll
    for (int q = 0; q < 10; ++q) {
      float4 t = *(const float4*)(rowp + q * 4);
      w[q * 4] = t.x; w[q * 4 + 1] = t.y; w[q * 4 + 2] = t.z; w[q * 4 + 3] = t.w;
    }
#pragma unroll
    for (int r = 0; r < 4; ++r) {
      unsigned ki = (unsigned)(k - r);
      if (ki > 30u) continue;        // uniform branch
      const float* kwr = &sKw[ki * 31];
#pragma unroll
      for (int kj = 0; kj < 31; ++kj) {
        float kv = kwr[kj];
#pragma unroll
        for (int c = 0; c < 8; ++c) acc[r][c] += w[kj + c] * kv;
      }
    }
  }
#pragma unroll
  for (int r = 0; r < 4; ++r) {
    long obase = ((long)b * 256 + l0 + ty * 4 + r) * 2048 + m0 + tx * 8;
    *(float4*)(dc + obase) = make_float4(acc[r][0], acc[r][1], acc[r][2], acc[r][3]);
    *(float4*)(dc + obase + 4) = make_float4(acc[r][4], acc[r][5], acc[r][6], acc[r][7]);
  }
}

// ---------------- fused transposed conv (stride 2x16) ----------------
__global__ __launch_bounds__(256) void convT_k(
    const float* __restrict__ dc, const float* __restrict__ w,
    const float* __restrict__ wb, float* __restrict__ out)
{
  int j = blockIdx.x, b = blockIdx.y;
  __shared__ float sD[2048];
  __shared__ float sW[2048];
  int tid = threadIdx.x;
  const float* drow = dc + ((long)b * 256 + j) * 2048;
  for (int i = tid; i < 2048; i += 256) { sD[i] = drow[i]; sW[i] = w[i]; }
  __syncthreads();
  float cb = wb[0];
  int owlo = tid & 15, ohbase = tid >> 4;
#pragma unroll
  for (int q = 0; q < 4; ++q) {
    int oh = ohbase + q * 16;
    int i = oh >> 1, a = oh & 1;
    float acc = cb;
#pragma unroll 8
    for (int e = 0; e < 64; ++e)
      acc += sD[e * 32 + i] * sW[e * 32 + a * 16 + owlo];
    out[((long)b * 64 + oh) * 4096 + j * 16 + owlo] = acc;
  }
}

// ---------------- launcher ----------------
extern "C" void kernel_launch(void* const* d_in, const int* in_sizes, int n_in,
                              void* d_out, int out_size, void* d_ws, size_t ws_size,
                              hipStream_t stream)
{
  const float* x      = (const float*)d_in[0];
  const int*   mask   = (const int*)d_in[1];
  const float* proj_w = (const float*)d_in[2];
  const float* proj_b = (const float*)d_in[3];
  const float* pos    = (const float*)d_in[4];
  const float* Wip    = (const float*)d_in[5];   // (1,2,8192,2048)
  const float* convw  = (const float*)d_in[6];
  const float* convb  = (const float*)d_in[7];
  const float* Wx     = (const float*)d_in[8];   // (1,2,160,4096)
  const float* Wdt    = (const float*)d_in[9];   // (1,2,4096,128)
  const float* bdt    = (const float*)d_in[10];
  const float* Alog   = (const float*)d_in[11];
  const float* Dpv    = (const float*)d_in[12];
  const float* Wout   = (const float*)d_in[13];  // (1,2,2048,4096)
  const float* lng    = (const float*)d_in[14];
  const float* lnb    = (const float*)d_in[15];
  const float* dkw    = (const float*)d_in[16];
  const float* ctw    = (const float*)d_in[17];
  const float* ctb    = (const float*)d_in[18];
  float* out = (float*)d_out;

  // workspace layout (bytes)
  char* p = (char*)d_ws;
  u16*   xz_bf   = (u16*)p;            // 33.5M u16 (67MB); later ob fp32 alias
  float* ob      = (float*)p;          //   8.4M f (33.5MB), written after scan
  p += 67108864;
  u16*   u_bf    = (u16*)p;            // 16.7M u16 (33.5MB); later dc alias
  float* dc      = (float*)p;          //   4.2M f (16.8MB), written after scan
  p += 33554432;
  float* dt      = (float*)p; p += 67108864;   // 16.7M f
  float* xdbl    = (float*)p; p += 2621440;    // 0.66M f
  u16*   xdbl_bf = (u16*)p;  p += 1310720;     // 0.66M u16
  float* h       = (float*)p; p += 16777216;   // 4.2M f
  u16*   h_bf    = (u16*)p;  p += 8388608;     // 4.2M u16
  float* h2      = (float*)p; p += 16777216;   // 4.2M f
  u16*   y_bf    = (u16*)p;  p += 33554432;    // 16.7M u16
  u16*   Wpool   = (u16*)p;  p += 67108864;    // 33.5M u16 (Wip_bf then Wout_bf)
  u16*   Wx_bf   = (u16*)p;  p += 2621440;     // 1.31M u16
  u16*   Wdt_bf  = (u16*)p;  p += 2097152;     // 1.05M u16

  // weight converts (Wip now; Wout later into same pool)
  cvt_bf16_k<<<32768, 256, 0, stream>>>(Wip, Wpool, 8388608);
  cvt_bf16_k<<<1280, 256, 0, stream>>>(Wx, Wx_bf, 327680);
  cvt_bf16_k<<<1024, 256, 0, stream>>>(Wdt, Wdt_bf, 262144);

  // 1) patchify + pos embed
  patchify_k<<<dim3(256, 8), 256, 0, stream>>>(x, mask, proj_w, proj_b, pos, h, h_bf);

  // 2) in_proj: xz_bf[dir] = (dir? flip(h):h) @ Wip[dir]^T  (2048x8192, K=2048)
  mfma_gemm_k<0, 0, 1><<<dim3(64, 16, 2), 256, 0, stream>>>(
      h_bf, 0L, Wpool, (long)8192 * 2048, nullptr, 0L, xz_bf, (long)2048 * 8192,
      nullptr, 0, 8192, 2048, 2048, 1);

  // 3) depthwise conv1d + silu -> u_bf
  conv1d_silu_k<<<16384, 256, 0, stream>>>(xz_bf, convw, convb, u_bf);

  // 4) x_dbl = u @ Wx^T  (2048x160, K=4096), fp32 + bf16 mirror
  mfma_gemm_k<0, 1, 1><<<dim3(2, 16, 2), 256, 0, stream>>>(
      u_bf, (long)2048 * 4096, Wx_bf, (long)160 * 4096, xdbl, (long)2048 * 160,
      xdbl_bf, (long)2048 * 160, nullptr, 0, 160, 4096, 4096, 0);

  // 5) dt = softplus(x_dbl[:, :128] @ Wdt^T + bdt)  (2048x4096, K=128)
  mfma_gemm_k<1, 1, 0><<<dim3(32, 16, 2), 256, 0, stream>>>(
      xdbl_bf, (long)2048 * 160, Wdt_bf, (long)4096 * 128, dt, (long)2048 * 4096,
      nullptr, 0L, bdt, 4096, 4096, 128, 160, 0);

  // 6) selective scan + gating -> y_bf
  scan_k<<<256, 256, 0, stream>>>(dt, u_bf, xz_bf, xdbl, Alog, Dpv, y_bf);

  // convert Wout into the (now dead) Wip pool
  cvt_bf16_k<<<16384, 256, 0, stream>>>(Wout, Wpool, 4194304);

  // 7) out = y @ Wout^T  (2048x2048, K=4096)  [ob aliases xz_bf region]
  mfma_gemm_k<0, 1, 0><<<dim3(16, 16, 2), 256, 0, stream>>>(
      y_bf, (long)2048 * 4096, Wpool, (long)2048 * 4096, ob, (long)2048 * 2048,
      nullptr, 0L, nullptr, 0, 2048, 4096, 4096, 0);

  // 8) h2 = LN(h + o_fwd + flip(o_rev))
  add_ln_k<<<2048, 256, 0, stream>>>(h, ob, ob + (long)2048 * 2048, lng, lnb, h2);

  // 9) 31x31 same conv -> dc  [aliases u_bf region, dead]
  dec_conv31_k<<<dim3(16, 4, 8), 256, 0, stream>>>(h2, dkw, dc);

  // 10) fused transposed conv -> rec
  convT_k<<<dim3(256, 8), 256, 0, stream>>>(dc, ctw, ctb, out);

  // 11) second output: x passthrough
  hipMemcpyAsync(out + 2097152, x, (size_t)2097152 * 4,
                 hipMemcpyDeviceToDevice, stream);
}

// Round 5
// 889.736 us; speedup vs baseline: 4.2247x; 1.0660x over previous
//
#include <hip/hip_runtime.h>
#include <hip/hip_bf16.h>
#include <math.h>

typedef unsigned short u16;
typedef __attribute__((ext_vector_type(8))) short bf16x8;
typedef __attribute__((ext_vector_type(4))) float f32x4;

__device__ __forceinline__ float b2f(u16 v) {
  unsigned u = ((unsigned)v) << 16;
  return __builtin_bit_cast(float, u);
}
__device__ __forceinline__ u16 f2b(float f) {
  unsigned u = __builtin_bit_cast(unsigned, f);
  unsigned r = u + 0x7fffu + ((u >> 16) & 1u);
  return (u16)(r >> 16);
}
__device__ __forceinline__ void gload_lds16(const u16* g, u16* l) {
  __builtin_amdgcn_global_load_lds(
      (const __attribute__((address_space(1))) void*)g,
      (__attribute__((address_space(3))) void*)l, 16, 0, 0);
}

// ---------------- fp32 -> bf16 convert ----------------
__global__ __launch_bounds__(256) void cvt_bf16_k(const float* __restrict__ s,
                                                  u16* __restrict__ d, int n4) {
  int i = blockIdx.x * 256 + threadIdx.x;
  if (i < n4) {
    float4 v = ((const float4*)s)[i];
    ushort4 o;
    o.x = f2b(v.x); o.y = f2b(v.y); o.z = f2b(v.z); o.w = f2b(v.w);
    ((ushort4*)d)[i] = o;
  }
}

// ---------------- patchify + pos embed -> h fp32 + h_bf ----------------
__global__ __launch_bounds__(256) void patchify_k(
    const float* __restrict__ x, const int* __restrict__ mask,
    const float* __restrict__ pw, const float* __restrict__ pb,
    const float* __restrict__ pos, float* __restrict__ h, u16* __restrict__ hb)
{
  int g1 = blockIdx.x, b = blockIdx.y, tid = threadIdx.x;
  __shared__ float sX[64 * 17];
  __shared__ float sW[2048];
  for (int i = tid; i < 64 * 16; i += 256) {
    int r = i >> 4, c = i & 15;
    int gi = (b * 64 + r) * 4096 + g1 * 16 + c;
    sX[r * 17 + c] = mask[gi] ? 0.f : x[gi];
  }
  for (int i = tid; i < 2048; i += 256) sW[i] = pw[i];
  __syncthreads();
  for (int m = tid; m < 2048; m += 256) {
    int e = m >> 5, g0 = m & 31;
    float acc = pb[e];
    const float* w = &sW[e * 32];
#pragma unroll
    for (int kh = 0; kh < 2; ++kh)
#pragma unroll
      for (int kw = 0; kw < 16; ++kw)
        acc += sX[(2 * g0 + kh) * 17 + kw] * w[kh * 16 + kw];
    float v = acc + pos[g1 * 2048 + m];
    long o = ((long)b * 256 + g1) * 2048 + m;
    h[o] = v;
    hb[o] = f2b(v);
  }
}

// ---------------- bf16 MFMA GEMM: C[m,n] = sum_k A[m,k]*B[n,k] ----------------
template <int EPI, int F32OUT, int BFOUT>
__global__ __launch_bounds__(256) void mfma_gemm_k(
    const u16* __restrict__ A0, long aStride,
    const u16* __restrict__ B0, long bStride,
    float* __restrict__ C0, long cStride,
    u16* __restrict__ Cb0, long cbStride,
    const float* __restrict__ bias0, int biasStride,
    int N, int K, int lda, int flipDir1)
{
  __shared__ __align__(16) u16 As[2][4096];
  __shared__ __align__(16) u16 Bs[2][4096];
  const int dir = blockIdx.z;
  const u16* A = A0 + (long)dir * aStride;
  const u16* B = B0 + (long)dir * bStride;
  float* C = F32OUT ? (C0 + (long)dir * cStride) : nullptr;
  u16* Cb = BFOUT ? (Cb0 + (long)dir * cbStride) : nullptr;
  const float* bias = (EPI == 1) ? (bias0 + (long)dir * biasStride) : nullptr;
  const int flip = flipDir1 && (dir == 1);

  const int tid = threadIdx.x;
  const int wave = tid >> 6, lane = tid & 63;
  const int wr = wave >> 1, wc = wave & 1;
  const int bm = blockIdx.y * 128, bn = blockIdx.x * 128;
  const int lr = lane & 15, lq = lane >> 4;

  f32x4 acc[4][4];
#pragma unroll
  for (int i = 0; i < 4; ++i)
#pragma unroll
    for (int j = 0; j < 4; ++j) acc[i][j] = (f32x4){0.f, 0.f, 0.f, 0.f};

  const int nk = K >> 5;

  auto stage = [&](int buf, int k0) {
#pragma unroll
    for (int iss = 0; iss < 2; ++iss) {
      int ob = wave * 2048 + iss * 1024 + lane * 16;  // byte offset in tile
      int row = ob >> 6, kb = (ob >> 4) & 3;
      int rg = bm + row;
      rg = flip ? ((rg & ~255) | (255 - (rg & 255))) : rg;
      gload_lds16(A + (long)rg * lda + k0 + kb * 8,
                  &As[buf][wave * 1024 + iss * 512]);
      int rb = bn + row; rb = (rb < N) ? rb : (N - 1);
      gload_lds16(B + (long)rb * K + k0 + kb * 8,
                  &Bs[buf][wave * 1024 + iss * 512]);
    }
  };

  stage(0, 0);
  for (int kt = 0; kt < nk; ++kt) {
    __syncthreads();
    if (kt + 1 < nk) stage((kt + 1) & 1, (kt + 1) << 5);
    const int buf = kt & 1;
    bf16x8 av[4], bv[4];
#pragma unroll
    for (int i = 0; i < 4; ++i)
      av[i] = *(const bf16x8*)&As[buf][(wr * 64 + i * 16 + lr) * 32 + lq * 8];
#pragma unroll
    for (int j = 0; j < 4; ++j)
      bv[j] = *(const bf16x8*)&Bs[buf][(wc * 64 + j * 16 + lr) * 32 + lq * 8];
#pragma unroll
    for (int i = 0; i < 4; ++i)
#pragma unroll
      for (int j = 0; j < 4; ++j)
        acc[i][j] = __builtin_amdgcn_mfma_f32_16x16x32_bf16(av[i], bv[j],
                                                            acc[i][j], 0, 0, 0);
  }

#pragma unroll
  for (int i = 0; i < 4; ++i) {
    int r0 = bm + wr * 64 + i * 16 + lq * 4;
#pragma unroll
    for (int j = 0; j < 4; ++j) {
      int col = bn + wc * 64 + j * 16 + lr;
      if (col < N) {
        f32x4 v = acc[i][j];
#pragma unroll
        for (int r = 0; r < 4; ++r) {
          float xv = v[r];
          if (EPI == 1) {
            xv += bias[col];
            xv = (xv > 20.f) ? xv : log1pf(expf(xv));
          }
          if (F32OUT) C[(long)(r0 + r) * N + col] = xv;
          if (BFOUT) Cb[(long)(r0 + r) * N + col] = f2b(xv);
        }
      }
    }
  }
}

// ---------------- depthwise causal conv1d (DC=4) + bias + silu (bf16 io) -----
__global__ __launch_bounds__(256) void conv1d_silu_k(
    const u16* __restrict__ xz, const float* __restrict__ cw,
    const float* __restrict__ cb, u16* __restrict__ u)
{
  long idx = (long)blockIdx.x * 256 + threadIdx.x;
  int d4 = (int)(idx & 1023);
  int l  = (int)((idx >> 10) & 255);
  int b  = (int)((idx >> 18) & 7);
  int dir = (int)(idx >> 21);
  int d = d4 * 4;
  const float4* wv = reinterpret_cast<const float4*>(cw + ((long)dir * 4096 + d) * 4);
  float4 w0 = wv[0], w1 = wv[1], w2 = wv[2], w3 = wv[3];
  const float* cbp = cb + dir * 4096 + d;
  float a0 = cbp[0], a1 = cbp[1], a2 = cbp[2], a3 = cbp[3];
  long base = (((long)dir * 8 + b) * 256) * 8192 + d;
#pragma unroll
  for (int k = 0; k < 4; ++k) {
    int lk = l - 3 + k;
    if (lk < 0) continue;
    ushort4 xv = *reinterpret_cast<const ushort4*>(xz + base + (long)lk * 8192);
    a0 += b2f(xv.x) * ((const float*)&w0)[k];
    a1 += b2f(xv.y) * ((const float*)&w1)[k];
    a2 += b2f(xv.z) * ((const float*)&w2)[k];
    a3 += b2f(xv.w) * ((const float*)&w3)[k];
  }
  ushort4 r;
  r.x = f2b(a0 / (1.f + __expf(-a0)));
  r.y = f2b(a1 / (1.f + __expf(-a1)));
  r.z = f2b(a2 / (1.f + __expf(-a2)));
  r.w = f2b(a3 / (1.f + __expf(-a3)));
  *reinterpret_cast<ushort4*>(u + (((long)dir * 8 + b) * 256 + l) * 4096 + d) = r;
}

// ---------------- scan pass A: per-chunk local scan (zero init) --------------
// block = (dir, b, chunk, dtile256); writes y_pre = C.st_local + u*Dp (bf16),
// chunk end-state (16 f32) and chunk dt-sum.
__global__ __launch_bounds__(256) void scan_a_k(
    const float* __restrict__ dtbuf, const u16* __restrict__ ubuf,
    const float* __restrict__ xdbl, const float* __restrict__ A_log,
    const float* __restrict__ Dpv, u16* __restrict__ ypre,
    float* __restrict__ stend, float* __restrict__ dtsum)
{
  int blk = blockIdx.x;              // [dir][b][c][dtile] = 2*8*8*16
  int dtile = blk & 15, c = (blk >> 4) & 7, b = (blk >> 7) & 7, dir = blk >> 10;
  int tid = threadIdx.x;
  int d = dtile * 256 + tid;
  int db = dir * 8 + b;

  __shared__ float sB[32][16], sC[32][16];
  long r160 = (long)db * 256 * 160;
  for (int i = tid; i < 1024; i += 256) {
    int l = i >> 5, s = i & 31;
    float v = xdbl[r160 + (long)(c * 32 + l) * 160 + 128 + s];
    if (s < 16) sB[l][s] = v; else sC[l][s - 16] = v;
  }
  __syncthreads();

  float A[16], st[16];
  const float4* ap = (const float4*)(A_log + ((long)dir * 4096 + d) * 16);
#pragma unroll
  for (int q = 0; q < 4; ++q) {
    float4 t = ap[q];
    A[q * 4 + 0] = -__expf(t.x); A[q * 4 + 1] = -__expf(t.y);
    A[q * 4 + 2] = -__expf(t.z); A[q * 4 + 3] = -__expf(t.w);
  }
#pragma unroll
  for (int s = 0; s < 16; ++s) st[s] = 0.f;
  float Dpd = Dpv[dir * 4096 + d];

  long base = (long)db * 256 * 4096 + (long)c * 32 * 4096 + d;
  float dts = 0.f;
  for (int i = 0; i < 32; ++i) {
    float dtv = dtbuf[base + (long)i * 4096];
    float uv  = b2f(ubuf[base + (long)i * 4096]);
    dts += dtv;
    float du = dtv * uv;
    float y = 0.f;
#pragma unroll
    for (int s = 0; s < 16; ++s) {
      st[s] = st[s] * __expf(dtv * A[s]) + du * sB[i][s];
      y += st[s] * sC[i][s];
    }
    ypre[base + (long)i * 4096] = f2b(y + uv * Dpd);
  }
  long eb = ((long)(db * 8 + c) * 4096 + d) * 16;
  float4* ep = (float4*)(stend + eb);
#pragma unroll
  for (int q = 0; q < 4; ++q)
    ep[q] = make_float4(st[q * 4], st[q * 4 + 1], st[q * 4 + 2], st[q * 4 + 3]);
  dtsum[(long)(db * 8 + c) * 4096 + d] = dts;
}

// ---------------- scan pass B: chunk combine + correction + gating -----------
// block = (dir, b, dtile64), 512 threads = 8 chunks x 64 d (wave == chunk).
__global__ __launch_bounds__(512) void scan_b_k(
    const float* __restrict__ dtbuf, const u16* __restrict__ xzbf,
    const float* __restrict__ xdbl, const float* __restrict__ A_log,
    const float* __restrict__ stend, const float* __restrict__ dtsum,
    u16* __restrict__ ybuf)
{
  int blk = blockIdx.x;              // [dir][b][dtile64] = 2*8*64
  int dtile = blk & 63, b = (blk >> 6) & 7, dir = blk >> 9;
  int tid = threadIdx.x;
  int c = tid >> 6, dd = tid & 63;
  int d0 = dtile * 64, d = d0 + dd;
  int db = dir * 8 + b;

  __shared__ float sEnd[8][64][17];  // padded: stride 17 -> conflict-free
  __shared__ float sT[8][64];
  __shared__ float sC[256][16];

  long eBase = (long)db * 8 * 65536;   // 4096*16 per chunk
  for (int i = tid; i < 8192; i += 512) {
    int cc = i >> 10, rem = i & 1023, dd2 = rem >> 4, s = rem & 15;
    sEnd[cc][dd2][s] = stend[eBase + (long)cc * 65536 + (long)(d0 + dd2) * 16 + s];
  }
  {
    int cc = tid >> 6, dd2 = tid & 63;
    sT[cc][dd2] = dtsum[(long)(db * 8 + cc) * 4096 + d0 + dd2];
  }
  long r160 = (long)db * 256 * 160;
  for (int i = tid; i < 4096; i += 512) {
    int l = i >> 4, s = i & 15;
    sC[l][s] = xdbl[r160 + (long)l * 160 + 144 + s];
  }
  __syncthreads();

  float A[16];
  const float4* ap = (const float4*)(A_log + ((long)dir * 4096 + d) * 16);
#pragma unroll
  for (int q = 0; q < 4; ++q) {
    float4 t = ap[q];
    A[q * 4 + 0] = -__expf(t.x); A[q * 4 + 1] = -__expf(t.y);
    A[q * 4 + 2] = -__expf(t.z); A[q * 4 + 3] = -__expf(t.w);
  }
  float g[16];
#pragma unroll
  for (int s = 0; s < 16; ++s) g[s] = 0.f;
  for (int j = 0; j < c; ++j) {      // wave-uniform trip count
    float Tj = sT[j][dd];
#pragma unroll
    for (int s = 0; s < 16; ++s)
      g[s] = g[s] * __expf(A[s] * Tj) + sEnd[j][dd][s];
  }

  long base  = (long)db * 256 * 4096 + (long)c * 32 * 4096 + d;
  long zbase = (long)db * 256 * 8192 + (long)c * 32 * 8192 + 4096 + d;
  float cum = 0.f;
  if (c == 0) {                      // whole-wave: no correction needed
    for (int i = 0; i < 32; ++i) {
      float yp = b2f(ybuf[base + (long)i * 4096]);
      float zv = b2f(xzbf[zbase + (long)i * 8192]);
      float y = yp * (zv / (1.f + __expf(-zv)));
      ybuf[base + (long)i * 4096] = f2b(y);
    }
  } else {
    for (int i = 0; i < 32; ++i) {
      float dtv = dtbuf[base + (long)i * 4096];
      cum += dtv;
      float yp = b2f(ybuf[base + (long)i * 4096]);
      float corr = 0.f;
      const int l = c * 32 + i;
#pragma unroll
      for (int s = 0; s < 16; ++s)
        corr += sC[l][s] * __expf(A[s] * cum) * g[s];
      float zv = b2f(xzbf[zbase + (long)i * 8192]);
      float y = (yp + corr) * (zv / (1.f + __expf(-zv)));
      ybuf[base + (long)i * 4096] = f2b(y);
    }
  }
}

// ---------------- residual add (fwd + flipped rev) + LayerNorm ----------------
__global__ __launch_bounds__(256) void add_ln_k(
    const float* __restrict__ h, const float* __restrict__ o0,
    const float* __restrict__ o1, const float* __restrict__ g,
    const float* __restrict__ bta, float* __restrict__ h2)
{
  int row = blockIdx.x;
  int b = row >> 8, l = row & 255;
  long base = (long)row * 2048;
  long base1 = ((long)b * 256 + (255 - l)) * 2048;
  int t8 = threadIdx.x * 8;
  float v[8];
  float4 x0 = *(const float4*)(h + base + t8);
  float4 x1 = *(const float4*)(h + base + t8 + 4);
  float4 a0 = *(const float4*)(o0 + base + t8);
  float4 a1 = *(const float4*)(o0 + base + t8 + 4);
  float4 c0 = *(const float4*)(o1 + base1 + t8);
  float4 c1 = *(const float4*)(o1 + base1 + t8 + 4);
  v[0] = x0.x + a0.x + c0.x; v[1] = x0.y + a0.y + c0.y;
  v[2] = x0.z + a0.z + c0.z; v[3] = x0.w + a0.w + c0.w;
  v[4] = x1.x + a1.x + c1.x; v[5] = x1.y + a1.y + c1.y;
  v[6] = x1.z + a1.z + c1.z; v[7] = x1.w + a1.w + c1.w;
  float s = 0.f, ss = 0.f;
#pragma unroll
  for (int j = 0; j < 8; ++j) { s += v[j]; ss += v[j] * v[j]; }
#pragma unroll
  for (int off = 32; off >= 1; off >>= 1) {
    s += __shfl_xor(s, off, 64);
    ss += __shfl_xor(ss, off, 64);
  }
  __shared__ float red[8];
  int wid = threadIdx.x >> 6, lane = threadIdx.x & 63;
  if (lane == 0) { red[wid] = s; red[wid + 4] = ss; }
  __syncthreads();
  if (threadIdx.x == 0) {
    red[0] = red[0] + red[1] + red[2] + red[3];
    red[4] = red[4] + red[5] + red[6] + red[7];
  }
  __syncthreads();
  float mean = red[0] * (1.f / 2048.f);
  float var = red[4] * (1.f / 2048.f) - mean * mean;
  float inv = rsqrtf(var + 1e-5f);
  float o[8];
#pragma unroll
  for (int j = 0; j < 8; ++j)
    o[j] = (v[j] - mean) * inv * g[t8 + j] + bta[t8 + j];
  *(float4*)(h2 + base + t8) = make_float4(o[0], o[1], o[2], o[3]);
  *(float4*)(h2 + base + t8 + 4) = make_float4(o[4], o[5], o[6], o[7]);
}

// ---------------- 31x31 "same" conv, 64x128 tile, 4x8 per thread -------------
__global__ __launch_bounds__(256) void dec_conv31_k(
    const float* __restrict__ h2, const float* __restrict__ kw,
    float* __restrict__ dc)
{
  __shared__ float sIn[94 * 162];   // 60912 B
  __shared__ float sKw[961];        //  3844 B
  int b = blockIdx.z;
  int l0 = blockIdx.y * 64;
  int m0 = blockIdx.x * 128;
  int tid = threadIdx.x;
  const float* src = h2 + (long)b * 256 * 2048;
  for (int i = tid; i < 961; i += 256) sKw[i] = kw[i];
  for (int i = tid; i < 94 * 162; i += 256) {
    int r = i / 162, c = i - r * 162;
    int gl = l0 + r - 15, gm = m0 + c - 15;
    float v = 0.f;
    if (c < 158 && gl >= 0 && gl < 256 && gm >= 0 && gm < 2048)
      v = src[(long)gl * 2048 + gm];
    sIn[i] = v;
  }
  __syncthreads();
  int tx = tid & 15, ty = tid >> 4;
  float acc[4][8];
#pragma unroll
  for (int r = 0; r < 4; ++r)
#pragma unroll
    for (int c = 0; c < 8; ++c) acc[r][c] = 0.f;

#pragma unroll 1
  for (int k = 0; k < 34; ++k) {
    const float* rowp = &sIn[(ty * 4 + k) * 162 + tx * 8];
    float w[40];
#pragma unroll
    for (int q = 0; q < 10; ++q) {
      float4 t = *(const float4*)(rowp + q * 4);
      w[q * 4] = t.x; w[q * 4 + 1] = t.y; w[q * 4 + 2] = t.z; w[q * 4 + 3] = t.w;
    }
#pragma unroll
    for (int r = 0; r < 4; ++r) {
      unsigned ki = (unsigned)(k - r);
      if (ki > 30u) continue;
      const float* kwr = &sKw[ki * 31];
#pragma unroll
      for (int kj = 0; kj < 31; ++kj) {
        float kv = kwr[kj];
#pragma unroll
        for (int c = 0; c < 8; ++c) acc[r][c] += w[kj + c] * kv;
      }
    }
  }
#pragma unroll
  for (int r = 0; r < 4; ++r) {
    long obase = ((long)b * 256 + l0 + ty * 4 + r) * 2048 + m0 + tx * 8;
    *(float4*)(dc + obase) = make_float4(acc[r][0], acc[r][1], acc[r][2], acc[r][3]);
    *(float4*)(dc + obase + 4) = make_float4(acc[r][4], acc[r][5], acc[r][6], acc[r][7]);
  }
}

// ---------------- fused transposed conv (stride 2x16) ----------------
__global__ __launch_bounds__(256) void convT_k(
    const float* __restrict__ dc, const float* __restrict__ w,
    const float* __restrict__ wb, float* __restrict__ out)
{
  int j = blockIdx.x, b = blockIdx.y;
  __shared__ float sD[2048];
  __shared__ float sW[2048];
  int tid = threadIdx.x;
  const float* drow = dc + ((long)b * 256 + j) * 2048;
  for (int i = tid; i < 2048; i += 256) { sD[i] = drow[i]; sW[i] = w[i]; }
  __syncthreads();
  float cb = wb[0];
  int owlo = tid & 15, ohbase = tid >> 4;
#pragma unroll
  for (int q = 0; q < 4; ++q) {
    int oh = ohbase + q * 16;
    int i = oh >> 1, a = oh & 1;
    float acc = cb;
#pragma unroll 8
    for (int e = 0; e < 64; ++e)
      acc += sD[e * 32 + i] * sW[e * 32 + a * 16 + owlo];
    out[((long)b * 64 + oh) * 4096 + j * 16 + owlo] = acc;
  }
}

// ---------------- launcher ----------------
extern "C" void kernel_launch(void* const* d_in, const int* in_sizes, int n_in,
                              void* d_out, int out_size, void* d_ws, size_t ws_size,
                              hipStream_t stream)
{
  const float* x      = (const float*)d_in[0];
  const int*   mask   = (const int*)d_in[1];
  const float* proj_w = (const float*)d_in[2];
  const float* proj_b = (const float*)d_in[3];
  const float* pos    = (const float*)d_in[4];
  const float* Wip    = (const float*)d_in[5];   // (1,2,8192,2048)
  const float* convw  = (const float*)d_in[6];
  const float* convb  = (const float*)d_in[7];
  const float* Wx     = (const float*)d_in[8];   // (1,2,160,4096)
  const float* Wdt    = (const float*)d_in[9];   // (1,2,4096,128)
  const float* bdt    = (const float*)d_in[10];
  const float* Alog   = (const float*)d_in[11];
  const float* Dpv    = (const float*)d_in[12];
  const float* Wout   = (const float*)d_in[13];  // (1,2,2048,4096)
  const float* lng    = (const float*)d_in[14];
  const float* lnb    = (const float*)d_in[15];
  const float* dkw    = (const float*)d_in[16];
  const float* ctw    = (const float*)d_in[17];
  const float* ctb    = (const float*)d_in[18];
  float* out = (float*)d_out;

  // workspace layout (bytes)
  char* p = (char*)d_ws;
  u16*   xz_bf   = (u16*)p;            // 33.5M u16 (67MB); later ob fp32 alias
  float* ob      = (float*)p;
  p += 67108864;
  u16*   u_bf    = (u16*)p;            // 16.7M u16 (33.5MB); later dc alias
  float* dc      = (float*)p;
  p += 33554432;
  float* dt      = (float*)p; p += 67108864;   // 16.7M f
  float* xdbl    = (float*)p; p += 2621440;    // 0.66M f
  u16*   xdbl_bf = (u16*)p;  p += 1310720;     // 0.66M u16
  float* h       = (float*)p; p += 16777216;   // 4.2M f
  u16*   h_bf    = (u16*)p;  p += 8388608;     // 4.2M u16
  float* h2      = (float*)p; p += 16777216;   // 4.2M f (also scan dtsum scratch)
  u16*   y_bf    = (u16*)p;  p += 33554432;    // 16.7M u16
  u16*   Wpool   = (u16*)p;  p += 67108864;    // Wip_bf; later Wout_bf (1st half)
  u16*   Wx_bf   = (u16*)p;  p += 2621440;
  u16*   Wdt_bf  = (u16*)p;  p += 2097152;

  // scan scratch (aliases of dead regions):
  float* st_end = (float*)(Wpool + 16777216);  // 2nd half of Wpool, 33.55 MB
  float* dtsum  = h2;                          // h2 not written until add_ln

  // weight converts (Wip now; Wout later into same pool)
  cvt_bf16_k<<<32768, 256, 0, stream>>>(Wip, Wpool, 8388608);
  cvt_bf16_k<<<1280, 256, 0, stream>>>(Wx, Wx_bf, 327680);
  cvt_bf16_k<<<1024, 256, 0, stream>>>(Wdt, Wdt_bf, 262144);

  // 1) patchify + pos embed
  patchify_k<<<dim3(256, 8), 256, 0, stream>>>(x, mask, proj_w, proj_b, pos, h, h_bf);

  // 2) in_proj: xz_bf[dir] = (dir? flip(h):h) @ Wip[dir]^T  (2048x8192, K=2048)
  mfma_gemm_k<0, 0, 1><<<dim3(64, 16, 2), 256, 0, stream>>>(
      h_bf, 0L, Wpool, (long)8192 * 2048, nullptr, 0L, xz_bf, (long)2048 * 8192,
      nullptr, 0, 8192, 2048, 2048, 1);

  // 3) depthwise conv1d + silu -> u_bf
  conv1d_silu_k<<<16384, 256, 0, stream>>>(xz_bf, convw, convb, u_bf);

  // 4) x_dbl = u @ Wx^T  (2048x160, K=4096), fp32 + bf16 mirror
  mfma_gemm_k<0, 1, 1><<<dim3(2, 16, 2), 256, 0, stream>>>(
      u_bf, (long)2048 * 4096, Wx_bf, (long)160 * 4096, xdbl, (long)2048 * 160,
      xdbl_bf, (long)2048 * 160, nullptr, 0, 160, 4096, 4096, 0);

  // 5) dt = softplus(x_dbl[:, :128] @ Wdt^T + bdt)  (2048x4096, K=128)
  mfma_gemm_k<1, 1, 0><<<dim3(32, 16, 2), 256, 0, stream>>>(
      xdbl_bf, (long)2048 * 160, Wdt_bf, (long)4096 * 128, dt, (long)2048 * 4096,
      nullptr, 0L, bdt, 4096, 4096, 128, 160, 0);

  // 6) chunked selective scan: local pass + combine/correction pass
  scan_a_k<<<2048, 256, 0, stream>>>(dt, u_bf, xdbl, Alog, Dpv, y_bf, st_end, dtsum);
  scan_b_k<<<1024, 512, 0, stream>>>(dt, xz_bf, xdbl, Alog, st_end, dtsum, y_bf);

  // convert Wout into the (now dead) first half of Wpool
  cvt_bf16_k<<<16384, 256, 0, stream>>>(Wout, Wpool, 4194304);

  // 7) out = y @ Wout^T  (2048x2048, K=4096)  [ob aliases xz_bf region]
  mfma_gemm_k<0, 1, 0><<<dim3(16, 16, 2), 256, 0, stream>>>(
      y_bf, (long)2048 * 4096, Wpool, (long)2048 * 4096, ob, (long)2048 * 2048,
      nullptr, 0L, nullptr, 0, 2048, 4096, 4096, 0);

  // 8) h2 = LN(h + o_fwd + flip(o_rev))   [overwrites dtsum scratch — scan done]
  add_ln_k<<<2048, 256, 0, stream>>>(h, ob, ob + (long)2048 * 2048, lng, lnb, h2);

  // 9) 31x31 same conv -> dc  [aliases u_bf region, dead]
  dec_conv31_k<<<dim3(16, 4, 8), 256, 0, stream>>>(h2, dkw, dc);

  // 10) fused transposed conv -> rec
  convT_k<<<dim3(256, 8), 256, 0, stream>>>(dc, ctw, ctb, out);

  // 11) second output: x passthrough
  hipMemcpyAsync(out + 2097152, x, (size_t)2097152 * 4,
                 hipMemcpyDeviceToDevice, stream);
}

// Round 6
// 864.265 us; speedup vs baseline: 4.3492x; 1.0295x over previous
//
#include <hip/hip_runtime.h>
#include <hip/hip_bf16.h>
#include <math.h>

typedef unsigned short u16;
typedef __attribute__((ext_vector_type(8))) short bf16x8;
typedef __attribute__((ext_vector_type(4))) float f32x4;

__device__ __forceinline__ float b2f(u16 v) {
  unsigned u = ((unsigned)v) << 16;
  return __builtin_bit_cast(float, u);
}
__device__ __forceinline__ u16 f2b(float f) {
  unsigned u = __builtin_bit_cast(unsigned, f);
  unsigned r = u + 0x7fffu + ((u >> 16) & 1u);
  return (u16)(r >> 16);
}
__device__ __forceinline__ void gload_lds16(const u16* g, u16* l) {
  __builtin_amdgcn_global_load_lds(
      (const __attribute__((address_space(1))) void*)g,
      (__attribute__((address_space(3))) void*)l, 16, 0, 0);
}

// ---------------- fp32 -> bf16 convert ----------------
__global__ __launch_bounds__(256) void cvt_bf16_k(const float* __restrict__ s,
                                                  u16* __restrict__ d, int n4) {
  int i = blockIdx.x * 256 + threadIdx.x;
  if (i < n4) {
    float4 v = ((const float4*)s)[i];
    ushort4 o;
    o.x = f2b(v.x); o.y = f2b(v.y); o.z = f2b(v.z); o.w = f2b(v.w);
    ((ushort4*)d)[i] = o;
  }
}

// ---------------- patchify + pos embed -> h fp32 + h_bf ----------------
__global__ __launch_bounds__(256) void patchify_k(
    const float* __restrict__ x, const int* __restrict__ mask,
    const float* __restrict__ pw, const float* __restrict__ pb,
    const float* __restrict__ pos, float* __restrict__ h, u16* __restrict__ hb)
{
  int g1 = blockIdx.x, b = blockIdx.y, tid = threadIdx.x;
  __shared__ float sX[64 * 17];
  __shared__ float sW[2048];
  for (int i = tid; i < 64 * 16; i += 256) {
    int r = i >> 4, c = i & 15;
    int gi = (b * 64 + r) * 4096 + g1 * 16 + c;
    sX[r * 17 + c] = mask[gi] ? 0.f : x[gi];
  }
  for (int i = tid; i < 2048; i += 256) sW[i] = pw[i];
  __syncthreads();
  for (int m = tid; m < 2048; m += 256) {
    int e = m >> 5, g0 = m & 31;
    float acc = pb[e];
    const float* w = &sW[e * 32];
#pragma unroll
    for (int kh = 0; kh < 2; ++kh)
#pragma unroll
      for (int kw = 0; kw < 16; ++kw)
        acc += sX[(2 * g0 + kh) * 17 + kw] * w[kh * 16 + kw];
    float v = acc + pos[g1 * 2048 + m];
    long o = ((long)b * 256 + g1) * 2048 + m;
    h[o] = v;
    hb[o] = f2b(v);
  }
}

// ========== 256x256x(BK=64) 8-wave MFMA GEMM for in_proj =====================
// xz_bf[dir] = (dir? flip(h):h) @ Wip[dir]^T ; M=2048, N=8192, K=2048.
// T2: LDS swizzle (linear gload_lds dest + inverse-swz global src + swz read)
// T4: counted vmcnt(8) double-buffer (never drain to 0 in loop)
// T5: setprio around MFMA clusters. Raw s_barrier + sched_barrier pins.
__global__ __launch_bounds__(512, 2) void gemm256_k(
    const u16* __restrict__ A0,               // h_bf (2048 x 2048)
    const u16* __restrict__ B0, long bStride, // Wip_bf (8192 x 2048) per dir
    u16* __restrict__ C0, long cStride)       // xz_bf (2048 x 8192) per dir
{
  constexpr int K = 2048, N = 8192, LDA = 2048;
  __shared__ __align__(16) u16 As[2][16384];  // 2 x 256x64 bf16 (32 KB each)
  __shared__ __align__(16) u16 Bs[2][16384];
  const int dir = blockIdx.z;
  const u16* A = A0;
  const u16* B = B0 + (long)dir * bStride;
  u16* C = C0 + (long)dir * cStride;
  const int flip = dir;

  const int tid = threadIdx.x;
  const int wave = tid >> 6, lane = tid & 63;
  const int wr = wave >> 2, wc = wave & 3;    // 2 x 4 wave grid, 128x64 each
  const int bm = blockIdx.y * 256, bn = blockIdx.x * 256;
  const int lr = lane & 15, lq = lane >> 4;

  f32x4 acc[8][4];
#pragma unroll
  for (int i = 0; i < 8; ++i)
#pragma unroll
    for (int j = 0; j < 4; ++j) acc[i][j] = (f32x4){0.f, 0.f, 0.f, 0.f};

  // stage K-tile kt into buf: 8 gload_lds/thread; LDS linear, source
  // pre-swizzled so that LDS granule (row, s) holds global granule s^(row&7).
  auto stage = [&](int buf, int kt) {
    int k0 = kt << 6;
#pragma unroll
    for (int hf = 0; hf < 2; ++hf)
#pragma unroll
      for (int j = 0; j < 2; ++j) {
        int g = j * 512 + tid;                 // granule in half-tile [0,1024)
        int rl = hf * 128 + (g >> 3);          // local row 0..255
        int gr = (g & 7) ^ ((g >> 3) & 7);     // source granule (inverse swz)
        int ar = flip ? (bm + 255 - rl) : (bm + rl);
        gload_lds16(A + (long)ar * LDA + k0 + gr * 8,
                    &As[buf][hf * 8192 + g * 8]);
        gload_lds16(B + (long)(bn + rl) * K + k0 + gr * 8,
                    &Bs[buf][hf * 8192 + g * 8]);
      }
  };

  const int nk = K >> 6;                       // 32 K-tiles
  stage(0, 0);
  for (int kt = 0; kt < nk; ++kt) {
    // entry barrier: all waves done reading buf (kt+1)&1 (used at kt-1)
    __builtin_amdgcn_s_barrier();
    __builtin_amdgcn_sched_barrier(0);
    if (kt + 1 < nk) {
      stage((kt + 1) & 1, kt + 1);
      asm volatile("s_waitcnt vmcnt(8)" ::: "memory");  // tile kt landed
    } else {
      asm volatile("s_waitcnt vmcnt(0)" ::: "memory");
    }
    __builtin_amdgcn_sched_barrier(0);
    __builtin_amdgcn_s_barrier();              // tile kt visible to all waves
    __builtin_amdgcn_sched_barrier(0);
    const int buf = kt & 1;
#pragma unroll
    for (int h = 0; h < 2; ++h) {
      bf16x8 av[8], bv[4];
#pragma unroll
      for (int i = 0; i < 8; ++i) {
        int row = wr * 128 + i * 16 + lr;
        av[i] = *(const bf16x8*)
            &As[buf][(row * 64 + h * 32 + lq * 8) ^ ((row & 7) << 3)];
      }
#pragma unroll
      for (int j = 0; j < 4; ++j) {
        int row = wc * 64 + j * 16 + lr;
        bv[j] = *(const bf16x8*)
            &Bs[buf][(row * 64 + h * 32 + lq * 8) ^ ((row & 7) << 3)];
      }
      __builtin_amdgcn_s_setprio(1);
#pragma unroll
      for (int i = 0; i < 8; ++i)
#pragma unroll
        for (int j = 0; j < 4; ++j)
          acc[i][j] = __builtin_amdgcn_mfma_f32_16x16x32_bf16(
              av[i], bv[j], acc[i][j], 0, 0, 0);
      __builtin_amdgcn_s_setprio(0);
    }
  }

#pragma unroll
  for (int i = 0; i < 8; ++i) {
    int r0 = bm + wr * 128 + i * 16 + lq * 4;
#pragma unroll
    for (int j = 0; j < 4; ++j) {
      int col = bn + wc * 64 + j * 16 + lr;
      f32x4 v = acc[i][j];
#pragma unroll
      for (int r = 0; r < 4; ++r)
        C[(long)(r0 + r) * N + col] = f2b(v[r]);
    }
  }
}

// ---------------- bf16 MFMA GEMM (128x128, m97 structure) ----------------
template <int EPI, int F32OUT, int BFOUT>
__global__ __launch_bounds__(256) void mfma_gemm_k(
    const u16* __restrict__ A0, long aStride,
    const u16* __restrict__ B0, long bStride,
    float* __restrict__ C0, long cStride,
    u16* __restrict__ Cb0, long cbStride,
    const float* __restrict__ bias0, int biasStride,
    int N, int K, int lda, int flipDir1)
{
  __shared__ __align__(16) u16 As[2][4096];
  __shared__ __align__(16) u16 Bs[2][4096];
  const int dir = blockIdx.z;
  const u16* A = A0 + (long)dir * aStride;
  const u16* B = B0 + (long)dir * bStride;
  float* C = F32OUT ? (C0 + (long)dir * cStride) : nullptr;
  u16* Cb = BFOUT ? (Cb0 + (long)dir * cbStride) : nullptr;
  const float* bias = (EPI == 1) ? (bias0 + (long)dir * biasStride) : nullptr;
  const int flip = flipDir1 && (dir == 1);

  const int tid = threadIdx.x;
  const int wave = tid >> 6, lane = tid & 63;
  const int wr = wave >> 1, wc = wave & 1;
  const int bm = blockIdx.y * 128, bn = blockIdx.x * 128;
  const int lr = lane & 15, lq = lane >> 4;

  f32x4 acc[4][4];
#pragma unroll
  for (int i = 0; i < 4; ++i)
#pragma unroll
    for (int j = 0; j < 4; ++j) acc[i][j] = (f32x4){0.f, 0.f, 0.f, 0.f};

  const int nk = K >> 5;

  auto stage = [&](int buf, int k0) {
#pragma unroll
    for (int iss = 0; iss < 2; ++iss) {
      int ob = wave * 2048 + iss * 1024 + lane * 16;  // byte offset in tile
      int row = ob >> 6, kb = (ob >> 4) & 3;
      int rg = bm + row;
      rg = flip ? ((rg & ~255) | (255 - (rg & 255))) : rg;
      gload_lds16(A + (long)rg * lda + k0 + kb * 8,
                  &As[buf][wave * 1024 + iss * 512]);
      int rb = bn + row; rb = (rb < N) ? rb : (N - 1);
      gload_lds16(B + (long)rb * K + k0 + kb * 8,
                  &Bs[buf][wave * 1024 + iss * 512]);
    }
  };

  stage(0, 0);
  for (int kt = 0; kt < nk; ++kt) {
    __syncthreads();
    if (kt + 1 < nk) stage((kt + 1) & 1, (kt + 1) << 5);
    const int buf = kt & 1;
    bf16x8 av[4], bv[4];
#pragma unroll
    for (int i = 0; i < 4; ++i)
      av[i] = *(const bf16x8*)&As[buf][(wr * 64 + i * 16 + lr) * 32 + lq * 8];
#pragma unroll
    for (int j = 0; j < 4; ++j)
      bv[j] = *(const bf16x8*)&Bs[buf][(wc * 64 + j * 16 + lr) * 32 + lq * 8];
#pragma unroll
    for (int i = 0; i < 4; ++i)
#pragma unroll
      for (int j = 0; j < 4; ++j)
        acc[i][j] = __builtin_amdgcn_mfma_f32_16x16x32_bf16(av[i], bv[j],
                                                            acc[i][j], 0, 0, 0);
  }

#pragma unroll
  for (int i = 0; i < 4; ++i) {
    int r0 = bm + wr * 64 + i * 16 + lq * 4;
#pragma unroll
    for (int j = 0; j < 4; ++j) {
      int col = bn + wc * 64 + j * 16 + lr;
      if (col < N) {
        f32x4 v = acc[i][j];
#pragma unroll
        for (int r = 0; r < 4; ++r) {
          float xv = v[r];
          if (EPI == 1) {
            xv += bias[col];
            xv = (xv > 20.f) ? xv : log1pf(expf(xv));
          }
          if (F32OUT) C[(long)(r0 + r) * N + col] = xv;
          if (BFOUT) Cb[(long)(r0 + r) * N + col] = f2b(xv);
        }
      }
    }
  }
}

// ---------------- depthwise causal conv1d (DC=4) + bias + silu (bf16 io) -----
__global__ __launch_bounds__(256) void conv1d_silu_k(
    const u16* __restrict__ xz, const float* __restrict__ cw,
    const float* __restrict__ cb, u16* __restrict__ u)
{
  long idx = (long)blockIdx.x * 256 + threadIdx.x;
  int d4 = (int)(idx & 1023);
  int l  = (int)((idx >> 10) & 255);
  int b  = (int)((idx >> 18) & 7);
  int dir = (int)(idx >> 21);
  int d = d4 * 4;
  const float4* wv = reinterpret_cast<const float4*>(cw + ((long)dir * 4096 + d) * 4);
  float4 w0 = wv[0], w1 = wv[1], w2 = wv[2], w3 = wv[3];
  const float* cbp = cb + dir * 4096 + d;
  float a0 = cbp[0], a1 = cbp[1], a2 = cbp[2], a3 = cbp[3];
  long base = (((long)dir * 8 + b) * 256) * 8192 + d;
#pragma unroll
  for (int k = 0; k < 4; ++k) {
    int lk = l - 3 + k;
    if (lk < 0) continue;
    ushort4 xv = *reinterpret_cast<const ushort4*>(xz + base + (long)lk * 8192);
    a0 += b2f(xv.x) * ((const float*)&w0)[k];
    a1 += b2f(xv.y) * ((const float*)&w1)[k];
    a2 += b2f(xv.z) * ((const float*)&w2)[k];
    a3 += b2f(xv.w) * ((const float*)&w3)[k];
  }
  ushort4 r;
  r.x = f2b(a0 / (1.f + __expf(-a0)));
  r.y = f2b(a1 / (1.f + __expf(-a1)));
  r.z = f2b(a2 / (1.f + __expf(-a2)));
  r.w = f2b(a3 / (1.f + __expf(-a3)));
  *reinterpret_cast<ushort4*>(u + (((long)dir * 8 + b) * 256 + l) * 4096 + d) = r;
}

// ---------------- scan pass A: per-chunk local scan (zero init) --------------
__global__ __launch_bounds__(256) void scan_a_k(
    const float* __restrict__ dtbuf, const u16* __restrict__ ubuf,
    const float* __restrict__ xdbl, const float* __restrict__ A_log,
    const float* __restrict__ Dpv, u16* __restrict__ ypre,
    float* __restrict__ stend, float* __restrict__ dtsum)
{
  int blk = blockIdx.x;              // [dir][b][c][dtile] = 2*8*8*16
  int dtile = blk & 15, c = (blk >> 4) & 7, b = (blk >> 7) & 7, dir = blk >> 10;
  int tid = threadIdx.x;
  int d = dtile * 256 + tid;
  int db = dir * 8 + b;

  __shared__ float sB[32][16], sC[32][16];
  long r160 = (long)db * 256 * 160;
  for (int i = tid; i < 1024; i += 256) {
    int l = i >> 5, s = i & 31;
    float v = xdbl[r160 + (long)(c * 32 + l) * 160 + 128 + s];
    if (s < 16) sB[l][s] = v; else sC[l][s - 16] = v;
  }
  __syncthreads();

  float A[16], st[16];
  const float4* ap = (const float4*)(A_log + ((long)dir * 4096 + d) * 16);
#pragma unroll
  for (int q = 0; q < 4; ++q) {
    float4 t = ap[q];
    A[q * 4 + 0] = -__expf(t.x); A[q * 4 + 1] = -__expf(t.y);
    A[q * 4 + 2] = -__expf(t.z); A[q * 4 + 3] = -__expf(t.w);
  }
#pragma unroll
  for (int s = 0; s < 16; ++s) st[s] = 0.f;
  float Dpd = Dpv[dir * 4096 + d];

  long base = (long)db * 256 * 4096 + (long)c * 32 * 4096 + d;
  float dts = 0.f;
  for (int i = 0; i < 32; ++i) {
    float dtv = dtbuf[base + (long)i * 4096];
    float uv  = b2f(ubuf[base + (long)i * 4096]);
    dts += dtv;
    float du = dtv * uv;
    float y = 0.f;
#pragma unroll
    for (int s = 0; s < 16; ++s) {
      st[s] = st[s] * __expf(dtv * A[s]) + du * sB[i][s];
      y += st[s] * sC[i][s];
    }
    ypre[base + (long)i * 4096] = f2b(y + uv * Dpd);
  }
  long eb = ((long)(db * 8 + c) * 4096 + d) * 16;
  float4* ep = (float4*)(stend + eb);
#pragma unroll
  for (int q = 0; q < 4; ++q)
    ep[q] = make_float4(st[q * 4], st[q * 4 + 1], st[q * 4 + 2], st[q * 4 + 3]);
  dtsum[(long)(db * 8 + c) * 4096 + d] = dts;
}

// ---------------- scan pass B: chunk combine + correction + gating -----------
__global__ __launch_bounds__(512) void scan_b_k(
    const float* __restrict__ dtbuf, const u16* __restrict__ xzbf,
    const float* __restrict__ xdbl, const float* __restrict__ A_log,
    const float* __restrict__ stend, const float* __restrict__ dtsum,
    u16* __restrict__ ybuf)
{
  int blk = blockIdx.x;              // [dir][b][dtile64] = 2*8*64
  int dtile = blk & 63, b = (blk >> 6) & 7, dir = blk >> 9;
  int tid = threadIdx.x;
  int c = tid >> 6, dd = tid & 63;
  int d0 = dtile * 64, d = d0 + dd;
  int db = dir * 8 + b;

  __shared__ float sEnd[8][64][17];
  __shared__ float sT[8][64];
  __shared__ float sC[256][16];

  long eBase = (long)db * 8 * 65536;
  for (int i = tid; i < 8192; i += 512) {
    int cc = i >> 10, rem = i & 1023, dd2 = rem >> 4, s = rem & 15;
    sEnd[cc][dd2][s] = stend[eBase + (long)cc * 65536 + (long)(d0 + dd2) * 16 + s];
  }
  {
    int cc = tid >> 6, dd2 = tid & 63;
    sT[cc][dd2] = dtsum[(long)(db * 8 + cc) * 4096 + d0 + dd2];
  }
  long r160 = (long)db * 256 * 160;
  for (int i = tid; i < 4096; i += 512) {
    int l = i >> 4, s = i & 15;
    sC[l][s] = xdbl[r160 + (long)l * 160 + 144 + s];
  }
  __syncthreads();

  float A[16];
  const float4* ap = (const float4*)(A_log + ((long)dir * 4096 + d) * 16);
#pragma unroll
  for (int q = 0; q < 4; ++q) {
    float4 t = ap[q];
    A[q * 4 + 0] = -__expf(t.x); A[q * 4 + 1] = -__expf(t.y);
    A[q * 4 + 2] = -__expf(t.z); A[q * 4 + 3] = -__expf(t.w);
  }
  float g[16];
#pragma unroll
  for (int s = 0; s < 16; ++s) g[s] = 0.f;
  for (int j = 0; j < c; ++j) {
    float Tj = sT[j][dd];
#pragma unroll
    for (int s = 0; s < 16; ++s)
      g[s] = g[s] * __expf(A[s] * Tj) + sEnd[j][dd][s];
  }

  long base  = (long)db * 256 * 4096 + (long)c * 32 * 4096 + d;
  long zbase = (long)db * 256 * 8192 + (long)c * 32 * 8192 + 4096 + d;
  float cum = 0.f;
  if (c == 0) {
    for (int i = 0; i < 32; ++i) {
      float yp = b2f(ybuf[base + (long)i * 4096]);
      float zv = b2f(xzbf[zbase + (long)i * 8192]);
      float y = yp * (zv / (1.f + __expf(-zv)));
      ybuf[base + (long)i * 4096] = f2b(y);
    }
  } else {
    for (int i = 0; i < 32; ++i) {
      float dtv = dtbuf[base + (long)i * 4096];
      cum += dtv;
      float yp = b2f(ybuf[base + (long)i * 4096]);
      float corr = 0.f;
      const int l = c * 32 + i;
#pragma unroll
      for (int s = 0; s < 16; ++s)
        corr += sC[l][s] * __expf(A[s] * cum) * g[s];
      float zv = b2f(xzbf[zbase + (long)i * 8192]);
      float y = (yp + corr) * (zv / (1.f + __expf(-zv)));
      ybuf[base + (long)i * 4096] = f2b(y);
    }
  }
}

// ---------------- residual add (fwd + flipped rev) + LayerNorm ----------------
__global__ __launch_bounds__(256) void add_ln_k(
    const float* __restrict__ h, const float* __restrict__ o0,
    const float* __restrict__ o1, const float* __restrict__ g,
    const float* __restrict__ bta, float* __restrict__ h2)
{
  int row = blockIdx.x;
  int b = row >> 8, l = row & 255;
  long base = (long)row * 2048;
  long base1 = ((long)b * 256 + (255 - l)) * 2048;
  int t8 = threadIdx.x * 8;
  float v[8];
  float4 x0 = *(const float4*)(h + base + t8);
  float4 x1 = *(const float4*)(h + base + t8 + 4);
  float4 a0 = *(const float4*)(o0 + base + t8);
  float4 a1 = *(const float4*)(o0 + base + t8 + 4);
  float4 c0 = *(const float4*)(o1 + base1 + t8);
  float4 c1 = *(const float4*)(o1 + base1 + t8 + 4);
  v[0] = x0.x + a0.x + c0.x; v[1] = x0.y + a0.y + c0.y;
  v[2] = x0.z + a0.z + c0.z; v[3] = x0.w + a0.w + c0.w;
  v[4] = x1.x + a1.x + c1.x; v[5] = x1.y + a1.y + c1.y;
  v[6] = x1.z + a1.z + c1.z; v[7] = x1.w + a1.w + c1.w;
  float s = 0.f, ss = 0.f;
#pragma unroll
  for (int j = 0; j < 8; ++j) { s += v[j]; ss += v[j] * v[j]; }
#pragma unroll
  for (int off = 32; off >= 1; off >>= 1) {
    s += __shfl_xor(s, off, 64);
    ss += __shfl_xor(ss, off, 64);
  }
  __shared__ float red[8];
  int wid = threadIdx.x >> 6, lane = threadIdx.x & 63;
  if (lane == 0) { red[wid] = s; red[wid + 4] = ss; }
  __syncthreads();
  if (threadIdx.x == 0) {
    red[0] = red[0] + red[1] + red[2] + red[3];
    red[4] = red[4] + red[5] + red[6] + red[7];
  }
  __syncthreads();
  float mean = red[0] * (1.f / 2048.f);
  float var = red[4] * (1.f / 2048.f) - mean * mean;
  float inv = rsqrtf(var + 1e-5f);
  float o[8];
#pragma unroll
  for (int j = 0; j < 8; ++j)
    o[j] = (v[j] - mean) * inv * g[t8 + j] + bta[t8 + j];
  *(float4*)(h2 + base + t8) = make_float4(o[0], o[1], o[2], o[3]);
  *(float4*)(h2 + base + t8 + 4) = make_float4(o[4], o[5], o[6], o[7]);
}

// ---------------- 31x31 "same" conv, 64x128 tile, 4x8 per thread -------------
__global__ __launch_bounds__(256) void dec_conv31_k(
    const float* __restrict__ h2, const float* __restrict__ kw,
    float* __restrict__ dc)
{
  __shared__ float sIn[94 * 162];
  __shared__ float sKw[961];
  int b = blockIdx.z;
  int l0 = blockIdx.y * 64;
  int m0 = blockIdx.x * 128;
  int tid = threadIdx.x;
  const float* src = h2 + (long)b * 256 * 2048;
  for (int i = tid; i < 961; i += 256) sKw[i] = kw[i];
  for (int i = tid; i < 94 * 162; i += 256) {
    int r = i / 162, c = i - r * 162;
    int gl = l0 + r - 15, gm = m0 + c - 15;
    float v = 0.f;
    if (c < 158 && gl >= 0 && gl < 256 && gm >= 0 && gm < 2048)
      v = src[(long)gl * 2048 + gm];
    sIn[i] = v;
  }
  __syncthreads();
  int tx = tid & 15, ty = tid >> 4;
  float acc[4][8];
#pragma unroll
  for (int r = 0; r < 4; ++r)
#pragma unroll
    for (int c = 0; c < 8; ++c) acc[r][c] = 0.f;

#pragma unroll 1
  for (int k = 0; k < 34; ++k) {
    const float* rowp = &sIn[(ty * 4 + k) * 162 + tx * 8];
    float w[40];
#pragma unroll
    for (int q = 0; q < 10; ++q) {
      float4 t = *(const float4*)(rowp + q * 4);
      w[q * 4] = t.x; w[q * 4 + 1] = t.y; w[q * 4 + 2] = t.z; w[q * 4 + 3] = t.w;
    }
#pragma unroll
    for (int r = 0; r < 4; ++r) {
      unsigned ki = (unsigned)(k - r);
      if (ki > 30u) continue;
      const float* kwr = &sKw[ki * 31];
#pragma unroll
      for (int kj = 0; kj < 31; ++kj) {
        float kv = kwr[kj];
#pragma unroll
        for (int c = 0; c < 8; ++c) acc[r][c] += w[kj + c] * kv;
      }
    }
  }
#pragma unroll
  for (int r = 0; r < 4; ++r) {
    long obase = ((long)b * 256 + l0 + ty * 4 + r) * 2048 + m0 + tx * 8;
    *(float4*)(dc + obase) = make_float4(acc[r][0], acc[r][1], acc[r][2], acc[r][3]);
    *(float4*)(dc + obase + 4) = make_float4(acc[r][4], acc[r][5], acc[r][6], acc[r][7]);
  }
}

// ---------------- fused transposed conv (stride 2x16) ----------------
__global__ __launch_bounds__(256) void convT_k(
    const float* __restrict__ dc, const float* __restrict__ w,
    const float* __restrict__ wb, float* __restrict__ out)
{
  int j = blockIdx.x, b = blockIdx.y;
  __shared__ float sD[2048];
  __shared__ float sW[2048];
  int tid = threadIdx.x;
  const float* drow = dc + ((long)b * 256 + j) * 2048;
  for (int i = tid; i < 2048; i += 256) { sD[i] = drow[i]; sW[i] = w[i]; }
  __syncthreads();
  float cb = wb[0];
  int owlo = tid & 15, ohbase = tid >> 4;
#pragma unroll
  for (int q = 0; q < 4; ++q) {
    int oh = ohbase + q * 16;
    int i = oh >> 1, a = oh & 1;
    float acc = cb;
#pragma unroll 8
    for (int e = 0; e < 64; ++e)
      acc += sD[e * 32 + i] * sW[e * 32 + a * 16 + owlo];
    out[((long)b * 64 + oh) * 4096 + j * 16 + owlo] = acc;
  }
}

// ---------------- launcher ----------------
extern "C" void kernel_launch(void* const* d_in, const int* in_sizes, int n_in,
                              void* d_out, int out_size, void* d_ws, size_t ws_size,
                              hipStream_t stream)
{
  const float* x      = (const float*)d_in[0];
  const int*   mask   = (const int*)d_in[1];
  const float* proj_w = (const float*)d_in[2];
  const float* proj_b = (const float*)d_in[3];
  const float* pos    = (const float*)d_in[4];
  const float* Wip    = (const float*)d_in[5];   // (1,2,8192,2048)
  const float* convw  = (const float*)d_in[6];
  const float* convb  = (const float*)d_in[7];
  const float* Wx     = (const float*)d_in[8];   // (1,2,160,4096)
  const float* Wdt    = (const float*)d_in[9];   // (1,2,4096,128)
  const float* bdt    = (const float*)d_in[10];
  const float* Alog   = (const float*)d_in[11];
  const float* Dpv    = (const float*)d_in[12];
  const float* Wout   = (const float*)d_in[13];  // (1,2,2048,4096)
  const float* lng    = (const float*)d_in[14];
  const float* lnb    = (const float*)d_in[15];
  const float* dkw    = (const float*)d_in[16];
  const float* ctw    = (const float*)d_in[17];
  const float* ctb    = (const float*)d_in[18];
  float* out = (float*)d_out;

  // workspace layout (bytes)
  char* p = (char*)d_ws;
  u16*   xz_bf   = (u16*)p;            // 33.5M u16 (67MB); later ob fp32 alias
  float* ob      = (float*)p;
  p += 67108864;
  u16*   u_bf    = (u16*)p;            // 16.7M u16 (33.5MB); later dc alias
  float* dc      = (float*)p;
  p += 33554432;
  float* dt      = (float*)p; p += 67108864;   // 16.7M f
  float* xdbl    = (float*)p; p += 2621440;    // 0.66M f
  u16*   xdbl_bf = (u16*)p;  p += 1310720;     // 0.66M u16
  float* h       = (float*)p; p += 16777216;   // 4.2M f
  u16*   h_bf    = (u16*)p;  p += 8388608;     // 4.2M u16
  float* h2      = (float*)p; p += 16777216;   // 4.2M f (also scan dtsum scratch)
  u16*   y_bf    = (u16*)p;  p += 33554432;    // 16.7M u16
  u16*   Wpool   = (u16*)p;  p += 67108864;    // Wip_bf; later Wout_bf (1st half)
  u16*   Wx_bf   = (u16*)p;  p += 2621440;
  u16*   Wdt_bf  = (u16*)p;  p += 2097152;

  // scan scratch (aliases of dead regions):
  float* st_end = (float*)(Wpool + 16777216);  // 2nd half of Wpool
  float* dtsum  = h2;                          // h2 not written until add_ln

  // weight converts (Wip now; Wout later into same pool)
  cvt_bf16_k<<<32768, 256, 0, stream>>>(Wip, Wpool, 8388608);
  cvt_bf16_k<<<1280, 256, 0, stream>>>(Wx, Wx_bf, 327680);
  cvt_bf16_k<<<1024, 256, 0, stream>>>(Wdt, Wdt_bf, 262144);

  // 1) patchify + pos embed
  patchify_k<<<dim3(256, 8), 256, 0, stream>>>(x, mask, proj_w, proj_b, pos, h, h_bf);

  // 2) in_proj (256^2 counted-vmcnt kernel): xz_bf[dir] = (dir? flip(h):h) @ Wip[dir]^T
  gemm256_k<<<dim3(32, 8, 2), 512, 0, stream>>>(
      h_bf, Wpool, (long)8192 * 2048, xz_bf, (long)2048 * 8192);

  // 3) depthwise conv1d + silu -> u_bf
  conv1d_silu_k<<<16384, 256, 0, stream>>>(xz_bf, convw, convb, u_bf);

  // 4) x_dbl = u @ Wx^T  (2048x160, K=4096), fp32 + bf16 mirror
  mfma_gemm_k<0, 1, 1><<<dim3(2, 16, 2), 256, 0, stream>>>(
      u_bf, (long)2048 * 4096, Wx_bf, (long)160 * 4096, xdbl, (long)2048 * 160,
      xdbl_bf, (long)2048 * 160, nullptr, 0, 160, 4096, 4096, 0);

  // 5) dt = softplus(x_dbl[:, :128] @ Wdt^T + bdt)  (2048x4096, K=128)
  mfma_gemm_k<1, 1, 0><<<dim3(32, 16, 2), 256, 0, stream>>>(
      xdbl_bf, (long)2048 * 160, Wdt_bf, (long)4096 * 128, dt, (long)2048 * 4096,
      nullptr, 0L, bdt, 4096, 4096, 128, 160, 0);

  // 6) chunked selective scan: local pass + combine/correction pass
  scan_a_k<<<2048, 256, 0, stream>>>(dt, u_bf, xdbl, Alog, Dpv, y_bf, st_end, dtsum);
  scan_b_k<<<1024, 512, 0, stream>>>(dt, xz_bf, xdbl, Alog, st_end, dtsum, y_bf);

  // convert Wout into the (now dead) first half of Wpool
  cvt_bf16_k<<<16384, 256, 0, stream>>>(Wout, Wpool, 4194304);

  // 7) out = y @ Wout^T  (2048x2048, K=4096)  [ob aliases xz_bf region]
  mfma_gemm_k<0, 1, 0><<<dim3(16, 16, 2), 256, 0, stream>>>(
      y_bf, (long)2048 * 4096, Wpool, (long)2048 * 4096, ob, (long)2048 * 2048,
      nullptr, 0L, nullptr, 0, 2048, 4096, 4096, 0);

  // 8) h2 = LN(h + o_fwd + flip(o_rev))
  add_ln_k<<<2048, 256, 0, stream>>>(h, ob, ob + (long)2048 * 2048, lng, lnb, h2);

  // 9) 31x31 same conv -> dc  [aliases u_bf region, dead]
  dec_conv31_k<<<dim3(16, 4, 8), 256, 0, stream>>>(h2, dkw, dc);

  // 10) fused transposed conv -> rec
  convT_k<<<dim3(256, 8), 256, 0, stream>>>(dc, ctw, ctb, out);

  // 11) second output: x passthrough
  hipMemcpyAsync(out + 2097152, x, (size_t)2097152 * 4,
                 hipMemcpyDeviceToDevice, stream);
}

// Round 7
// 814.923 us; speedup vs baseline: 4.6125x; 1.0605x over previous
//
#include <hip/hip_runtime.h>
#include <hip/hip_bf16.h>
#include <math.h>

typedef unsigned short u16;
typedef __attribute__((ext_vector_type(8))) short bf16x8;
typedef __attribute__((ext_vector_type(4))) float f32x4;

__device__ __forceinline__ float b2f(u16 v) {
  unsigned u = ((unsigned)v) << 16;
  return __builtin_bit_cast(float, u);
}
__device__ __forceinline__ u16 f2b(float f) {
  unsigned u = __builtin_bit_cast(unsigned, f);
  unsigned r = u + 0x7fffu + ((u >> 16) & 1u);
  return (u16)(r >> 16);
}
__device__ __forceinline__ void gload_lds16(const u16* g, u16* l) {
  __builtin_amdgcn_global_load_lds(
      (const __attribute__((address_space(1))) void*)g,
      (__attribute__((address_space(3))) void*)l, 16, 0, 0);
}

// ---------------- fp32 -> bf16 convert ----------------
__global__ __launch_bounds__(256) void cvt_bf16_k(const float* __restrict__ s,
                                                  u16* __restrict__ d, int n4) {
  int i = blockIdx.x * 256 + threadIdx.x;
  if (i < n4) {
    float4 v = ((const float4*)s)[i];
    ushort4 o;
    o.x = f2b(v.x); o.y = f2b(v.y); o.z = f2b(v.z); o.w = f2b(v.w);
    ((ushort4*)d)[i] = o;
  }
}

// ---------------- patchify + pos embed -> h fp32 + h_bf ----------------
__global__ __launch_bounds__(256) void patchify_k(
    const float* __restrict__ x, const int* __restrict__ mask,
    const float* __restrict__ pw, const float* __restrict__ pb,
    const float* __restrict__ pos, float* __restrict__ h, u16* __restrict__ hb)
{
  int g1 = blockIdx.x, b = blockIdx.y, tid = threadIdx.x;
  __shared__ float sX[64 * 17];
  __shared__ float sW[2048];
  for (int i = tid; i < 64 * 16; i += 256) {
    int r = i >> 4, c = i & 15;
    int gi = (b * 64 + r) * 4096 + g1 * 16 + c;
    sX[r * 17 + c] = mask[gi] ? 0.f : x[gi];
  }
  for (int i = tid; i < 2048; i += 256) sW[i] = pw[i];
  __syncthreads();
  for (int m = tid; m < 2048; m += 256) {
    int e = m >> 5, g0 = m & 31;
    float acc = pb[e];
    const float* w = &sW[e * 32];
#pragma unroll
    for (int kh = 0; kh < 2; ++kh)
#pragma unroll
      for (int kw = 0; kw < 16; ++kw)
        acc += sX[(2 * g0 + kh) * 17 + kw] * w[kh * 16 + kw];
    float v = acc + pos[g1 * 2048 + m];
    long o = ((long)b * 256 + g1) * 2048 + m;
    h[o] = v;
    hb[o] = f2b(v);
  }
}

// ========== 256x256x(BK=64) 8-wave MFMA GEMM for in_proj =====================
__global__ __launch_bounds__(512, 2) void gemm256_k(
    const u16* __restrict__ A0,               // h_bf (2048 x 2048)
    const u16* __restrict__ B0, long bStride, // Wip_bf (8192 x 2048) per dir
    u16* __restrict__ C0, long cStride)       // xz_bf (2048 x 8192) per dir
{
  constexpr int K = 2048, N = 8192, LDA = 2048;
  __shared__ __align__(16) u16 As[2][16384];
  __shared__ __align__(16) u16 Bs[2][16384];
  const int dir = blockIdx.z;
  const u16* A = A0;
  const u16* B = B0 + (long)dir * bStride;
  u16* C = C0 + (long)dir * cStride;
  const int flip = dir;

  const int tid = threadIdx.x;
  const int wave = tid >> 6, lane = tid & 63;
  const int wr = wave >> 2, wc = wave & 3;
  const int bm = blockIdx.y * 256, bn = blockIdx.x * 256;
  const int lr = lane & 15, lq = lane >> 4;

  f32x4 acc[8][4];
#pragma unroll
  for (int i = 0; i < 8; ++i)
#pragma unroll
    for (int j = 0; j < 4; ++j) acc[i][j] = (f32x4){0.f, 0.f, 0.f, 0.f};

  auto stage = [&](int buf, int kt) {
    int k0 = kt << 6;
#pragma unroll
    for (int hf = 0; hf < 2; ++hf)
#pragma unroll
      for (int j = 0; j < 2; ++j) {
        int g = j * 512 + tid;
        int rl = hf * 128 + (g >> 3);
        int gr = (g & 7) ^ ((g >> 3) & 7);
        int ar = flip ? (bm + 255 - rl) : (bm + rl);
        gload_lds16(A + (long)ar * LDA + k0 + gr * 8,
                    &As[buf][hf * 8192 + g * 8]);
        gload_lds16(B + (long)(bn + rl) * K + k0 + gr * 8,
                    &Bs[buf][hf * 8192 + g * 8]);
      }
  };

  const int nk = K >> 6;
  stage(0, 0);
  for (int kt = 0; kt < nk; ++kt) {
    __builtin_amdgcn_s_barrier();
    __builtin_amdgcn_sched_barrier(0);
    if (kt + 1 < nk) {
      stage((kt + 1) & 1, kt + 1);
      asm volatile("s_waitcnt vmcnt(8)" ::: "memory");
    } else {
      asm volatile("s_waitcnt vmcnt(0)" ::: "memory");
    }
    __builtin_amdgcn_sched_barrier(0);
    __builtin_amdgcn_s_barrier();
    __builtin_amdgcn_sched_barrier(0);
    const int buf = kt & 1;
#pragma unroll
    for (int h = 0; h < 2; ++h) {
      bf16x8 av[8], bv[4];
#pragma unroll
      for (int i = 0; i < 8; ++i) {
        int row = wr * 128 + i * 16 + lr;
        av[i] = *(const bf16x8*)
            &As[buf][(row * 64 + h * 32 + lq * 8) ^ ((row & 7) << 3)];
      }
#pragma unroll
      for (int j = 0; j < 4; ++j) {
        int row = wc * 64 + j * 16 + lr;
        bv[j] = *(const bf16x8*)
            &Bs[buf][(row * 64 + h * 32 + lq * 8) ^ ((row & 7) << 3)];
      }
      __builtin_amdgcn_s_setprio(1);
#pragma unroll
      for (int i = 0; i < 8; ++i)
#pragma unroll
        for (int j = 0; j < 4; ++j)
          acc[i][j] = __builtin_amdgcn_mfma_f32_16x16x32_bf16(
              av[i], bv[j], acc[i][j], 0, 0, 0);
      __builtin_amdgcn_s_setprio(0);
    }
  }

#pragma unroll
  for (int i = 0; i < 8; ++i) {
    int r0 = bm + wr * 128 + i * 16 + lq * 4;
#pragma unroll
    for (int j = 0; j < 4; ++j) {
      int col = bn + wc * 64 + j * 16 + lr;
      f32x4 v = acc[i][j];
#pragma unroll
      for (int r = 0; r < 4; ++r)
        C[(long)(r0 + r) * N + col] = f2b(v[r]);
    }
  }
}

// ---------------- bf16 MFMA GEMM (128x128, m97 structure) ----------------
template <int EPI, int F32OUT, int BFOUT>
__global__ __launch_bounds__(256) void mfma_gemm_k(
    const u16* __restrict__ A0, long aStride,
    const u16* __restrict__ B0, long bStride,
    float* __restrict__ C0, long cStride,
    u16* __restrict__ Cb0, long cbStride,
    const float* __restrict__ bias0, int biasStride,
    int N, int K, int lda, int flipDir1)
{
  __shared__ __align__(16) u16 As[2][4096];
  __shared__ __align__(16) u16 Bs[2][4096];
  const int dir = blockIdx.z;
  const u16* A = A0 + (long)dir * aStride;
  const u16* B = B0 + (long)dir * bStride;
  float* C = F32OUT ? (C0 + (long)dir * cStride) : nullptr;
  u16* Cb = BFOUT ? (Cb0 + (long)dir * cbStride) : nullptr;
  const float* bias = (EPI == 1) ? (bias0 + (long)dir * biasStride) : nullptr;
  const int flip = flipDir1 && (dir == 1);

  const int tid = threadIdx.x;
  const int wave = tid >> 6, lane = tid & 63;
  const int wr = wave >> 1, wc = wave & 1;
  const int bm = blockIdx.y * 128, bn = blockIdx.x * 128;
  const int lr = lane & 15, lq = lane >> 4;

  f32x4 acc[4][4];
#pragma unroll
  for (int i = 0; i < 4; ++i)
#pragma unroll
    for (int j = 0; j < 4; ++j) acc[i][j] = (f32x4){0.f, 0.f, 0.f, 0.f};

  const int nk = K >> 5;

  auto stage = [&](int buf, int k0) {
#pragma unroll
    for (int iss = 0; iss < 2; ++iss) {
      int ob = wave * 2048 + iss * 1024 + lane * 16;
      int row = ob >> 6, kb = (ob >> 4) & 3;
      int rg = bm + row;
      rg = flip ? ((rg & ~255) | (255 - (rg & 255))) : rg;
      gload_lds16(A + (long)rg * lda + k0 + kb * 8,
                  &As[buf][wave * 1024 + iss * 512]);
      int rb = bn + row; rb = (rb < N) ? rb : (N - 1);
      gload_lds16(B + (long)rb * K + k0 + kb * 8,
                  &Bs[buf][wave * 1024 + iss * 512]);
    }
  };

  stage(0, 0);
  for (int kt = 0; kt < nk; ++kt) {
    __syncthreads();
    if (kt + 1 < nk) stage((kt + 1) & 1, (kt + 1) << 5);
    const int buf = kt & 1;
    bf16x8 av[4], bv[4];
#pragma unroll
    for (int i = 0; i < 4; ++i)
      av[i] = *(const bf16x8*)&As[buf][(wr * 64 + i * 16 + lr) * 32 + lq * 8];
#pragma unroll
    for (int j = 0; j < 4; ++j)
      bv[j] = *(const bf16x8*)&Bs[buf][(wc * 64 + j * 16 + lr) * 32 + lq * 8];
#pragma unroll
    for (int i = 0; i < 4; ++i)
#pragma unroll
      for (int j = 0; j < 4; ++j)
        acc[i][j] = __builtin_amdgcn_mfma_f32_16x16x32_bf16(av[i], bv[j],
                                                            acc[i][j], 0, 0, 0);
  }

#pragma unroll
  for (int i = 0; i < 4; ++i) {
    int r0 = bm + wr * 64 + i * 16 + lq * 4;
#pragma unroll
    for (int j = 0; j < 4; ++j) {
      int col = bn + wc * 64 + j * 16 + lr;
      if (col < N) {
        f32x4 v = acc[i][j];
#pragma unroll
        for (int r = 0; r < 4; ++r) {
          float xv = v[r];
          if (EPI == 1) {
            xv += bias[col];
            xv = (xv > 20.f) ? xv : log1pf(expf(xv));
          }
          if (F32OUT) C[(long)(r0 + r) * N + col] = xv;
          if (BFOUT) Cb[(long)(r0 + r) * N + col] = f2b(xv);
        }
      }
    }
  }
}

// ---------------- depthwise causal conv1d (DC=4) + bias + silu (bf16 io) -----
__global__ __launch_bounds__(256) void conv1d_silu_k(
    const u16* __restrict__ xz, const float* __restrict__ cw,
    const float* __restrict__ cb, u16* __restrict__ u)
{
  long idx = (long)blockIdx.x * 256 + threadIdx.x;
  int d4 = (int)(idx & 1023);
  int l  = (int)((idx >> 10) & 255);
  int b  = (int)((idx >> 18) & 7);
  int dir = (int)(idx >> 21);
  int d = d4 * 4;
  const float4* wv = reinterpret_cast<const float4*>(cw + ((long)dir * 4096 + d) * 4);
  float4 w0 = wv[0], w1 = wv[1], w2 = wv[2], w3 = wv[3];
  const float* cbp = cb + dir * 4096 + d;
  float a0 = cbp[0], a1 = cbp[1], a2 = cbp[2], a3 = cbp[3];
  long base = (((long)dir * 8 + b) * 256) * 8192 + d;
#pragma unroll
  for (int k = 0; k < 4; ++k) {
    int lk = l - 3 + k;
    if (lk < 0) continue;
    ushort4 xv = *reinterpret_cast<const ushort4*>(xz + base + (long)lk * 8192);
    a0 += b2f(xv.x) * ((const float*)&w0)[k];
    a1 += b2f(xv.y) * ((const float*)&w1)[k];
    a2 += b2f(xv.z) * ((const float*)&w2)[k];
    a3 += b2f(xv.w) * ((const float*)&w3)[k];
  }
  ushort4 r;
  r.x = f2b(a0 / (1.f + __expf(-a0)));
  r.y = f2b(a1 / (1.f + __expf(-a1)));
  r.z = f2b(a2 / (1.f + __expf(-a2)));
  r.w = f2b(a3 / (1.f + __expf(-a3)));
  *reinterpret_cast<ushort4*>(u + (((long)dir * 8 + b) * 256 + l) * 4096 + d) = r;
}

// ---------------- scan pass A: per-chunk local scan (zero init) --------------
__global__ __launch_bounds__(256) void scan_a_k(
    const float* __restrict__ dtbuf, const u16* __restrict__ ubuf,
    const float* __restrict__ xdbl, const float* __restrict__ A_log,
    const float* __restrict__ Dpv, u16* __restrict__ ypre,
    float* __restrict__ stend, float* __restrict__ dtsum)
{
  int blk = blockIdx.x;
  int dtile = blk & 15, c = (blk >> 4) & 7, b = (blk >> 7) & 7, dir = blk >> 10;
  int tid = threadIdx.x;
  int d = dtile * 256 + tid;
  int db = dir * 8 + b;

  __shared__ float sB[32][16], sC[32][16];
  long r160 = (long)db * 256 * 160;
  for (int i = tid; i < 1024; i += 256) {
    int l = i >> 5, s = i & 31;
    float v = xdbl[r160 + (long)(c * 32 + l) * 160 + 128 + s];
    if (s < 16) sB[l][s] = v; else sC[l][s - 16] = v;
  }
  __syncthreads();

  float A[16], st[16];
  const float4* ap = (const float4*)(A_log + ((long)dir * 4096 + d) * 16);
#pragma unroll
  for (int q = 0; q < 4; ++q) {
    float4 t = ap[q];
    A[q * 4 + 0] = -__expf(t.x); A[q * 4 + 1] = -__expf(t.y);
    A[q * 4 + 2] = -__expf(t.z); A[q * 4 + 3] = -__expf(t.w);
  }
#pragma unroll
  for (int s = 0; s < 16; ++s) st[s] = 0.f;
  float Dpd = Dpv[dir * 4096 + d];

  long base = (long)db * 256 * 4096 + (long)c * 32 * 4096 + d;
  float dts = 0.f;
  for (int i = 0; i < 32; ++i) {
    float dtv = dtbuf[base + (long)i * 4096];
    float uv  = b2f(ubuf[base + (long)i * 4096]);
    dts += dtv;
    float du = dtv * uv;
    float y = 0.f;
#pragma unroll
    for (int s = 0; s < 16; ++s) {
      st[s] = st[s] * __expf(dtv * A[s]) + du * sB[i][s];
      y += st[s] * sC[i][s];
    }
    ypre[base + (long)i * 4096] = f2b(y + uv * Dpd);
  }
  long eb = ((long)(db * 8 + c) * 4096 + d) * 16;
  float4* ep = (float4*)(stend + eb);
#pragma unroll
  for (int q = 0; q < 4; ++q)
    ep[q] = make_float4(st[q * 4], st[q * 4 + 1], st[q * 4 + 2], st[q * 4 + 3]);
  dtsum[(long)(db * 8 + c) * 4096 + d] = dts;
}

// ---------------- scan pass B: chunk combine + correction + gating -----------
__global__ __launch_bounds__(512) void scan_b_k(
    const float* __restrict__ dtbuf, const u16* __restrict__ xzbf,
    const float* __restrict__ xdbl, const float* __restrict__ A_log,
    const float* __restrict__ stend, const float* __restrict__ dtsum,
    u16* __restrict__ ybuf)
{
  int blk = blockIdx.x;
  int dtile = blk & 63, b = (blk >> 6) & 7, dir = blk >> 9;
  int tid = threadIdx.x;
  int c = tid >> 6, dd = tid & 63;
  int d0 = dtile * 64, d = d0 + dd;
  int db = dir * 8 + b;

  __shared__ float sEnd[8][64][17];
  __shared__ float sT[8][64];
  __shared__ float sC[256][16];

  long eBase = (long)db * 8 * 65536;
  for (int i = tid; i < 8192; i += 512) {
    int cc = i >> 10, rem = i & 1023, dd2 = rem >> 4, s = rem & 15;
    sEnd[cc][dd2][s] = stend[eBase + (long)cc * 65536 + (long)(d0 + dd2) * 16 + s];
  }
  {
    int cc = tid >> 6, dd2 = tid & 63;
    sT[cc][dd2] = dtsum[(long)(db * 8 + cc) * 4096 + d0 + dd2];
  }
  long r160 = (long)db * 256 * 160;
  for (int i = tid; i < 4096; i += 512) {
    int l = i >> 4, s = i & 15;
    sC[l][s] = xdbl[r160 + (long)l * 160 + 144 + s];
  }
  __syncthreads();

  float A[16];
  const float4* ap = (const float4*)(A_log + ((long)dir * 4096 + d) * 16);
#pragma unroll
  for (int q = 0; q < 4; ++q) {
    float4 t = ap[q];
    A[q * 4 + 0] = -__expf(t.x); A[q * 4 + 1] = -__expf(t.y);
    A[q * 4 + 2] = -__expf(t.z); A[q * 4 + 3] = -__expf(t.w);
  }
  float g[16];
#pragma unroll
  for (int s = 0; s < 16; ++s) g[s] = 0.f;
  for (int j = 0; j < c; ++j) {
    float Tj = sT[j][dd];
#pragma unroll
    for (int s = 0; s < 16; ++s)
      g[s] = g[s] * __expf(A[s] * Tj) + sEnd[j][dd][s];
  }

  long base  = (long)db * 256 * 4096 + (long)c * 32 * 4096 + d;
  long zbase = (long)db * 256 * 8192 + (long)c * 32 * 8192 + 4096 + d;
  float cum = 0.f;
  if (c == 0) {
    for (int i = 0; i < 32; ++i) {
      float yp = b2f(ybuf[base + (long)i * 4096]);
      float zv = b2f(xzbf[zbase + (long)i * 8192]);
      float y = yp * (zv / (1.f + __expf(-zv)));
      ybuf[base + (long)i * 4096] = f2b(y);
    }
  } else {
    for (int i = 0; i < 32; ++i) {
      float dtv = dtbuf[base + (long)i * 4096];
      cum += dtv;
      float yp = b2f(ybuf[base + (long)i * 4096]);
      float corr = 0.f;
      const int l = c * 32 + i;
#pragma unroll
      for (int s = 0; s < 16; ++s)
        corr += sC[l][s] * __expf(A[s] * cum) * g[s];
      float zv = b2f(xzbf[zbase + (long)i * 8192]);
      float y = (yp + corr) * (zv / (1.f + __expf(-zv)));
      ybuf[base + (long)i * 4096] = f2b(y);
    }
  }
}

// ---------------- residual add (fwd + flipped rev) + LayerNorm ----------------
__global__ __launch_bounds__(256) void add_ln_k(
    const float* __restrict__ h, const float* __restrict__ o0,
    const float* __restrict__ o1, const float* __restrict__ g,
    const float* __restrict__ bta, float* __restrict__ h2)
{
  int row = blockIdx.x;
  int b = row >> 8, l = row & 255;
  long base = (long)row * 2048;
  long base1 = ((long)b * 256 + (255 - l)) * 2048;
  int t8 = threadIdx.x * 8;
  float v[8];
  float4 x0 = *(const float4*)(h + base + t8);
  float4 x1 = *(const float4*)(h + base + t8 + 4);
  float4 a0 = *(const float4*)(o0 + base + t8);
  float4 a1 = *(const float4*)(o0 + base + t8 + 4);
  float4 c0 = *(const float4*)(o1 + base1 + t8);
  float4 c1 = *(const float4*)(o1 + base1 + t8 + 4);
  v[0] = x0.x + a0.x + c0.x; v[1] = x0.y + a0.y + c0.y;
  v[2] = x0.z + a0.z + c0.z; v[3] = x0.w + a0.w + c0.w;
  v[4] = x1.x + a1.x + c1.x; v[5] = x1.y + a1.y + c1.y;
  v[6] = x1.z + a1.z + c1.z; v[7] = x1.w + a1.w + c1.w;
  float s = 0.f, ss = 0.f;
#pragma unroll
  for (int j = 0; j < 8; ++j) { s += v[j]; ss += v[j] * v[j]; }
#pragma unroll
  for (int off = 32; off >= 1; off >>= 1) {
    s += __shfl_xor(s, off, 64);
    ss += __shfl_xor(ss, off, 64);
  }
  __shared__ float red[8];
  int wid = threadIdx.x >> 6, lane = threadIdx.x & 63;
  if (lane == 0) { red[wid] = s; red[wid + 4] = ss; }
  __syncthreads();
  if (threadIdx.x == 0) {
    red[0] = red[0] + red[1] + red[2] + red[3];
    red[4] = red[4] + red[5] + red[6] + red[7];
  }
  __syncthreads();
  float mean = red[0] * (1.f / 2048.f);
  float var = red[4] * (1.f / 2048.f) - mean * mean;
  float inv = rsqrtf(var + 1e-5f);
  float o[8];
#pragma unroll
  for (int j = 0; j < 8; ++j)
    o[j] = (v[j] - mean) * inv * g[t8 + j] + bta[t8 + j];
  *(float4*)(h2 + base + t8) = make_float4(o[0], o[1], o[2], o[3]);
  *(float4*)(h2 + base + t8 + 4) = make_float4(o[4], o[5], o[6], o[7]);
}

// ---------------- 31x31 "same" conv, 32x128 tile, bf16 LDS, 2x8/thread -------
// LDS 24.7 KB -> 4 blocks/CU co-resident (1024 blocks), 16 waves/CU.
// bf16 tile halves LDS traffic; lane layout distributes banks uniformly.
__global__ __launch_bounds__(256) void dec_conv31_k(
    const float* __restrict__ h2, const float* __restrict__ kw,
    float* __restrict__ dc)
{
  __shared__ u16 sIn[62 * 168];     // 20832 B
  __shared__ float sKw[961];        //  3844 B
  int b = blockIdx.z;
  int l0 = blockIdx.y * 32;
  int m0 = blockIdx.x * 128;
  int tid = threadIdx.x;
  const float* src = h2 + (long)b * 256 * 2048;
  for (int i = tid; i < 961; i += 256) sKw[i] = kw[i];
  for (int i = tid; i < 62 * 168; i += 256) {
    int r = i / 168, c = i - r * 168;
    int gl = l0 + r - 15, gm = m0 + c - 15;
    float v = 0.f;
    if (c < 158 && gl >= 0 && gl < 256 && gm >= 0 && gm < 2048)
      v = src[(long)gl * 2048 + gm];
    sIn[i] = f2b(v);
  }
  __syncthreads();
  int tx = tid & 15, ty = tid >> 4;   // thread: rows ty*2,ty*2+1 x cols tx*8..+7
  float acc[2][8];
#pragma unroll
  for (int r = 0; r < 2; ++r)
#pragma unroll
    for (int c = 0; c < 8; ++c) acc[r][c] = 0.f;

#pragma unroll 1
  for (int k = 0; k < 32; ++k) {
    const u16* rowp = &sIn[(ty * 2 + k) * 168 + tx * 8];
    float w[40];
#pragma unroll
    for (int q = 0; q < 5; ++q) {
      bf16x8 t = *(const bf16x8*)(rowp + q * 8);
#pragma unroll
      for (int e = 0; e < 8; ++e) w[q * 8 + e] = b2f((u16)t[e]);
    }
#pragma unroll
    for (int r = 0; r < 2; ++r) {
      unsigned ki = (unsigned)(k - r);
      if (ki > 30u) continue;        // uniform branch
      const float* kwr = &sKw[ki * 31];
#pragma unroll
      for (int kj = 0; kj < 31; ++kj) {
        float kv = kwr[kj];
#pragma unroll
        for (int c = 0; c < 8; ++c) acc[r][c] += w[kj + c] * kv;
      }
    }
  }
#pragma unroll
  for (int r = 0; r < 2; ++r) {
    long obase = ((long)b * 256 + l0 + ty * 2 + r) * 2048 + m0 + tx * 8;
    *(float4*)(dc + obase) = make_float4(acc[r][0], acc[r][1], acc[r][2], acc[r][3]);
    *(float4*)(dc + obase + 4) = make_float4(acc[r][4], acc[r][5], acc[r][6], acc[r][7]);
  }
}

// ---------------- fused transposed conv (stride 2x16) ----------------
__global__ __launch_bounds__(256) void convT_k(
    const float* __restrict__ dc, const float* __restrict__ w,
    const float* __restrict__ wb, float* __restrict__ out)
{
  int j = blockIdx.x, b = blockIdx.y;
  __shared__ float sD[2048];
  __shared__ float sW[2048];
  int tid = threadIdx.x;
  const float* drow = dc + ((long)b * 256 + j) * 2048;
  for (int i = tid; i < 2048; i += 256) { sD[i] = drow[i]; sW[i] = w[i]; }
  __syncthreads();
  float cb = wb[0];
  int owlo = tid & 15, ohbase = tid >> 4;
#pragma unroll
  for (int q = 0; q < 4; ++q) {
    int oh = ohbase + q * 16;
    int i = oh >> 1, a = oh & 1;
    float acc = cb;
#pragma unroll 8
    for (int e = 0; e < 64; ++e)
      acc += sD[e * 32 + i] * sW[e * 32 + a * 16 + owlo];
    out[((long)b * 64 + oh) * 4096 + j * 16 + owlo] = acc;
  }
}

// ---------------- launcher ----------------
extern "C" void kernel_launch(void* const* d_in, const int* in_sizes, int n_in,
                              void* d_out, int out_size, void* d_ws, size_t ws_size,
                              hipStream_t stream)
{
  const float* x      = (const float*)d_in[0];
  const int*   mask   = (const int*)d_in[1];
  const float* proj_w = (const float*)d_in[2];
  const float* proj_b = (const float*)d_in[3];
  const float* pos    = (const float*)d_in[4];
  const float* Wip    = (const float*)d_in[5];   // (1,2,8192,2048)
  const float* convw  = (const float*)d_in[6];
  const float* convb  = (const float*)d_in[7];
  const float* Wx     = (const float*)d_in[8];   // (1,2,160,4096)
  const float* Wdt    = (const float*)d_in[9];   // (1,2,4096,128)
  const float* bdt    = (const float*)d_in[10];
  const float* Alog   = (const float*)d_in[11];
  const float* Dpv    = (const float*)d_in[12];
  const float* Wout   = (const float*)d_in[13];  // (1,2,2048,4096)
  const float* lng    = (const float*)d_in[14];
  const float* lnb    = (const float*)d_in[15];
  const float* dkw    = (const float*)d_in[16];
  const float* ctw    = (const float*)d_in[17];
  const float* ctb    = (const float*)d_in[18];
  float* out = (float*)d_out;

  // workspace layout (bytes)
  char* p = (char*)d_ws;
  u16*   xz_bf   = (u16*)p;            // 33.5M u16 (67MB); later ob fp32 alias
  float* ob      = (float*)p;
  p += 67108864;
  u16*   u_bf    = (u16*)p;            // 16.7M u16 (33.5MB); later dc alias
  float* dc      = (float*)p;
  p += 33554432;
  float* dt      = (float*)p; p += 67108864;   // 16.7M f
  float* xdbl    = (float*)p; p += 2621440;    // 0.66M f
  u16*   xdbl_bf = (u16*)p;  p += 1310720;     // 0.66M u16
  float* h       = (float*)p; p += 16777216;   // 4.2M f
  u16*   h_bf    = (u16*)p;  p += 8388608;     // 4.2M u16
  float* h2      = (float*)p; p += 16777216;   // 4.2M f (also scan dtsum scratch)
  u16*   y_bf    = (u16*)p;  p += 33554432;    // 16.7M u16
  u16*   Wpool   = (u16*)p;  p += 67108864;    // Wip_bf; later Wout_bf (1st half)
  u16*   Wx_bf   = (u16*)p;  p += 2621440;
  u16*   Wdt_bf  = (u16*)p;  p += 2097152;

  // scan scratch (aliases of dead regions):
  float* st_end = (float*)(Wpool + 16777216);  // 2nd half of Wpool
  float* dtsum  = h2;                          // h2 not written until add_ln

  // weight converts (Wip now; Wout later into same pool)
  cvt_bf16_k<<<32768, 256, 0, stream>>>(Wip, Wpool, 8388608);
  cvt_bf16_k<<<1280, 256, 0, stream>>>(Wx, Wx_bf, 327680);
  cvt_bf16_k<<<1024, 256, 0, stream>>>(Wdt, Wdt_bf, 262144);

  // 1) patchify + pos embed
  patchify_k<<<dim3(256, 8), 256, 0, stream>>>(x, mask, proj_w, proj_b, pos, h, h_bf);

  // 2) in_proj (256^2 counted-vmcnt kernel)
  gemm256_k<<<dim3(32, 8, 2), 512, 0, stream>>>(
      h_bf, Wpool, (long)8192 * 2048, xz_bf, (long)2048 * 8192);

  // 3) depthwise conv1d + silu -> u_bf
  conv1d_silu_k<<<16384, 256, 0, stream>>>(xz_bf, convw, convb, u_bf);

  // 4) x_dbl = u @ Wx^T  (2048x160, K=4096), fp32 + bf16 mirror
  mfma_gemm_k<0, 1, 1><<<dim3(2, 16, 2), 256, 0, stream>>>(
      u_bf, (long)2048 * 4096, Wx_bf, (long)160 * 4096, xdbl, (long)2048 * 160,
      xdbl_bf, (long)2048 * 160, nullptr, 0, 160, 4096, 4096, 0);

  // 5) dt = softplus(x_dbl[:, :128] @ Wdt^T + bdt)  (2048x4096, K=128)
  mfma_gemm_k<1, 1, 0><<<dim3(32, 16, 2), 256, 0, stream>>>(
      xdbl_bf, (long)2048 * 160, Wdt_bf, (long)4096 * 128, dt, (long)2048 * 4096,
      nullptr, 0L, bdt, 4096, 4096, 128, 160, 0);

  // 6) chunked selective scan: local pass + combine/correction pass
  scan_a_k<<<2048, 256, 0, stream>>>(dt, u_bf, xdbl, Alog, Dpv, y_bf, st_end, dtsum);
  scan_b_k<<<1024, 512, 0, stream>>>(dt, xz_bf, xdbl, Alog, st_end, dtsum, y_bf);

  // convert Wout into the (now dead) first half of Wpool
  cvt_bf16_k<<<16384, 256, 0, stream>>>(Wout, Wpool, 4194304);

  // 7) out = y @ Wout^T  (2048x2048, K=4096)  [ob aliases xz_bf region]
  mfma_gemm_k<0, 1, 0><<<dim3(16, 16, 2), 256, 0, stream>>>(
      y_bf, (long)2048 * 4096, Wpool, (long)2048 * 4096, ob, (long)2048 * 2048,
      nullptr, 0L, nullptr, 0, 2048, 4096, 4096, 0);

  // 8) h2 = LN(h + o_fwd + flip(o_rev))
  add_ln_k<<<2048, 256, 0, stream>>>(h, ob, ob + (long)2048 * 2048, lng, lnb, h2);

  // 9) 31x31 same conv -> dc  [aliases u_bf region, dead]
  dec_conv31_k<<<dim3(16, 8, 8), 256, 0, stream>>>(h2, dkw, dc);

  // 10) fused transposed conv -> rec
  convT_k<<<dim3(256, 8), 256, 0, stream>>>(dc, ctw, ctb, out);

  // 11) second output: x passthrough
  hipMemcpyAsync(out + 2097152, x, (size_t)2097152 * 4,
                 hipMemcpyDeviceToDevice, stream);
}